// Round 9
// baseline (460.926 us; speedup 1.0000x reference)
//
#include <hip/hip_runtime.h>

#define NN 50000
#define NE 800000
#define NEA (NE + NN)

constexpr int H1 = 4, F1 = 128, HC1 = 256;
constexpr int HC2 = 128;

typedef unsigned short u16;
typedef unsigned int u32;
typedef __attribute__((ext_vector_type(8))) short bf16x8;
typedef __attribute__((ext_vector_type(4))) float f32x4;

__device__ __forceinline__ float bf2f(u16 h) {
    return __uint_as_float(((u32)h) << 16);
}
__device__ __forceinline__ u16 f2bf(float f) {
    u32 u = __float_as_uint(f);
    u32 r = (u + 0x7fffu + ((u >> 16) & 1u)) >> 16;   // RTN-even
    return (u16)r;
}

__device__ __forceinline__ int ld_edge(const int* e32, const long long* e64, int is64, long long idx) {
    return is64 ? (int)e64[idx] : e32[idx];
}

// ---------------- fused prep: x->bf16, W1/W2 pack, Wa = W @ att ----------------
__global__ __launch_bounds__(256) void k_prep(
    const float* __restrict__ x, const float* __restrict__ W1, const float* __restrict__ W2,
    const float* __restrict__ as1w, const float* __restrict__ ad1w,
    const float* __restrict__ as2w, const float* __restrict__ ad2w,
    u16* __restrict__ xb, u16* __restrict__ wp1, u16* __restrict__ wp2,
    float* __restrict__ wa1, float* __restrict__ wa2)
{
    const int b = blockIdx.x, tid = threadIdx.x;
    if (b < 3125) {                       // cvt: 3125*256*8 == NN*F1
        int i = b * 256 + tid;
        const float4* p = (const float4*)x + (size_t)i * 2;
        float4 a = p[0], c = p[1];
        ushort4 o0, o1;
        o0.x = f2bf(a.x); o0.y = f2bf(a.y); o0.z = f2bf(a.z); o0.w = f2bf(a.w);
        o1.x = f2bf(c.x); o1.y = f2bf(c.y); o1.z = f2bf(c.z); o1.w = f2bf(c.w);
        ((ushort4*)xb)[(size_t)i * 2] = o0;
        ((ushort4*)xb)[(size_t)i * 2 + 1] = o1;
    } else if (b < 3253) {                // wp1: [NK][256][4][8] <- W1[128][256]
        int o = (b - 3125) * 256 + tid;
        int j = o & 7, lk = (o >> 3) & 3, nn = (o >> 5) & 255, kc = o >> 13;
        int k = kc * 32 + lk * 8 + j;
        wp1[o] = f2bf(W1[(size_t)k * HC1 + nn]);
    } else if (b < 3381) {                // wp2: [NK][128][4][8] <- W2[256][128]
        int o = (b - 3253) * 256 + tid;
        int j = o & 7, lk = (o >> 3) & 3, nn = (o >> 5) & 127, kc = o >> 12;
        int k = kc * 32 + lk * 8 + j;
        wp2[o] = f2bf(W2[(size_t)k * HC2 + nn]);
    } else {                              // watt
        #pragma unroll
        for (int pp = 0; pp < 2; pp++) {
            int p = tid + pp * 256;       // 512 (k,h) pairs
            int k = p >> 2, h = p & 3;
            float s = 0.f, d = 0.f;
            for (int c = 0; c < 64; c++) {
                float wv = W1[(size_t)k * HC1 + h * 64 + c];
                s = fmaf(wv, as1w[h * 64 + c], s);
                d = fmaf(wv, ad1w[h * 64 + c], d);
            }
            wa1[h * 128 + k] = s;
            wa1[(4 + h) * 128 + k] = d;
        }
        {   // wa2 [256][2]
            int k = tid;
            float s = 0.f, d = 0.f;
            for (int c = 0; c < 128; c++) {
                float wv = W2[(size_t)k * HC2 + c];
                s = fmaf(wv, as2w[c], s);
                d = fmaf(wv, ad2w[c], d);
            }
            wa2[k * 2] = s;
            wa2[k * 2 + 1] = d;
        }
    }
}

// ---------------- CSR build (self-loops materialized at slot 0 of each row) ----------------
__global__ void k_zero_detect(int* __restrict__ p, const int* __restrict__ e32, int* __restrict__ flag) {
    int i = blockIdx.x * blockDim.x + threadIdx.x;
    if (i < NN) p[i] = 1;                 // degree starts at 1: self-loop
    if (i == 0) {
        int z = 1;
        for (int t = 0; t < 16; t++)
            if (e32[2 * t + 1] != 0) z = 0;
        *flag = z;
    }
}

__global__ void k_count(const int* __restrict__ e32, const long long* __restrict__ e64,
                        const int* __restrict__ flag, int* __restrict__ deg) {
    int e = blockIdx.x * blockDim.x + threadIdx.x;
    if (e >= NE) return;
    int is64 = *flag;
    int dst = ld_edge(e32, e64, is64, (long long)NE + e);
    atomicAdd(&deg[dst], 1);
}

__global__ __launch_bounds__(256) void k_part(const int* __restrict__ deg, int* __restrict__ bsum) {
    int i = blockIdx.x * 256 + threadIdx.x;
    int v = (i < NN) ? deg[i] : 0;
    #pragma unroll
    for (int off = 1; off < 64; off <<= 1) v += __shfl_xor(v, off);
    __shared__ int ws[4];
    if ((threadIdx.x & 63) == 0) ws[threadIdx.x >> 6] = v;
    __syncthreads();
    if (threadIdx.x == 0) bsum[blockIdx.x] = ws[0] + ws[1] + ws[2] + ws[3];
}

__global__ __launch_bounds__(256) void k_scanb(const int* __restrict__ bsum, int* __restrict__ boff,
                                               int* __restrict__ row_ptr, int NB) {
    const int tid = threadIdx.x;
    const int lane = tid & 63, wv = tid >> 6;
    int v = (tid < NB) ? bsum[tid] : 0;
    int x = v;
    #pragma unroll
    for (int off = 1; off < 64; off <<= 1) {
        int t = __shfl_up(x, off);
        if (lane >= off) x += t;
    }
    __shared__ int wsum[4], woff[4];
    if (lane == 63) wsum[wv] = x;
    __syncthreads();
    if (tid == 0) {
        int run = 0;
        #pragma unroll
        for (int j = 0; j < 4; j++) { woff[j] = run; run += wsum[j]; }
        row_ptr[NN] = run;
    }
    __syncthreads();
    if (tid < NB) boff[tid] = x - v + woff[wv];
}

__global__ __launch_bounds__(256) void k_addb(const int* __restrict__ deg, const int* __restrict__ boff,
                                              int* __restrict__ row_ptr, int* __restrict__ cursor,
                                              int* __restrict__ col) {
    const int tid = threadIdx.x;
    const int lane = tid & 63, wv = tid >> 6;
    int i = blockIdx.x * 256 + tid;
    int v = (i < NN) ? deg[i] : 0;
    int x = v;
    #pragma unroll
    for (int off = 1; off < 64; off <<= 1) {
        int t = __shfl_up(x, off);
        if (lane >= off) x += t;
    }
    __shared__ int wsum[4], woff[4];
    if (lane == 63) wsum[wv] = x;
    __syncthreads();
    if (tid == 0) {
        int run = 0;
        #pragma unroll
        for (int j = 0; j < 4; j++) { woff[j] = run; run += wsum[j]; }
    }
    __syncthreads();
    int excl = x - v + woff[wv] + boff[blockIdx.x];
    if (i < NN) {
        row_ptr[i] = excl;
        cursor[i] = excl + 1;    // slot 0 reserved for self-loop
        col[excl] = i;
    }
}

__global__ void k_fill(const int* __restrict__ e32, const long long* __restrict__ e64,
                       const int* __restrict__ flag, int* __restrict__ cursor, int* __restrict__ col) {
    int e = blockIdx.x * blockDim.x + threadIdx.x;
    if (e >= NE) return;
    int is64 = *flag;
    int src = ld_edge(e32, e64, is64, e);
    int dst = ld_edge(e32, e64, is64, (long long)NE + e);
    int pos = atomicAdd(&cursor[dst], 1);
    col[pos] = src;
}

// ---------------- pure MFMA GEMM; output in slice-major layout [NOUT/32][NN][32] ----------------
template <int K, int NOUT, int TPB>
__global__ __launch_bounds__(TPB) void k_gemm_mfma(
    const u16* __restrict__ Ab, const u16* __restrict__ Wp, u16* __restrict__ Hout, int M)
{
    constexpr int BM = 64, BK = 32;
    constexpr int NK = K / BK;
    constexpr int LDA = 40;
    __shared__ __align__(16) u16 As[2][BM * LDA];

    const int tid = threadIdx.x;
    const int w = tid >> 6;
    const int l = tid & 63;
    const int l15 = l & 15, lk = l >> 4;
    const int row0 = blockIdx.x * BM;
    const int col0 = w * 64;

    f32x4 acc[4][4];
    #pragma unroll
    for (int rt = 0; rt < 4; rt++)
        #pragma unroll
        for (int nt = 0; nt < 4; nt++)
            acc[rt][nt] = (f32x4){0.f, 0.f, 0.f, 0.f};

    auto stage = [&](int kc, int b) {
        #pragma unroll
        for (int i = tid; i < BM * 4; i += TPB) {
            int r = i >> 2, c = (i & 3) * 8;
            int gr = row0 + r;
            bf16x8 v = {0, 0, 0, 0, 0, 0, 0, 0};
            if (gr < M) v = *(const bf16x8*)(Ab + (size_t)gr * K + kc * BK + c);
            *(bf16x8*)&As[b][r * LDA + c] = v;
        }
    };
    auto loadB = [&](int kc, bf16x8* bf) {
        #pragma unroll
        for (int nt = 0; nt < 4; nt++)
            bf[nt] = *(const bf16x8*)(Wp + (((size_t)kc * NOUT + col0 + nt * 16 + l15) * 4 + lk) * 8);
    };

    bf16x8 bcur[4];
    loadB(0, bcur);
    stage(0, 0);
    for (int kc = 0; kc < NK; ++kc) {
        __syncthreads();
        bf16x8 afr[4];
        #pragma unroll
        for (int rt = 0; rt < 4; rt++)
            afr[rt] = *(const bf16x8*)&As[kc & 1][(rt * 16 + l15) * LDA + lk * 8];
        bf16x8 bnext[4];
        if (kc + 1 < NK) {
            loadB(kc + 1, bnext);
            stage(kc + 1, (kc + 1) & 1);
        }
        #pragma unroll
        for (int rt = 0; rt < 4; rt++)
            #pragma unroll
            for (int nt = 0; nt < 4; nt++)
                acc[rt][nt] = __builtin_amdgcn_mfma_f32_16x16x32_bf16(afr[rt], bcur[nt], acc[rt][nt], 0, 0, 0);
        if (kc + 1 < NK) {
            #pragma unroll
            for (int nt = 0; nt < 4; nt++) bcur[nt] = bnext[nt];
        }
    }

    // D layout col=l&15, row=(l>>4)*4+t  [m89-verified]; slice-major store
    #pragma unroll
    for (int rt = 0; rt < 4; rt++) {
        #pragma unroll
        for (int t = 0; t < 4; t++) {
            int gr = row0 + rt * 16 + lk * 4 + t;
            if (gr < M) {
                #pragma unroll
                for (int nt = 0; nt < 4; nt++) {
                    int c = col0 + nt * 16 + l15;
                    Hout[((size_t)(c >> 5) * NN + gr) * 32 + (c & 31)] = f2bf(acc[rt][nt][t]);
                }
            }
        }
    }
}

// ---------------- logits layer 1: as1/ad1 = xb @ Wa1  (Wa1 [8][128]) ----------------
__global__ __launch_bounds__(256) void k_logits1(
    const u16* __restrict__ xb, const float* __restrict__ wa1,
    float* __restrict__ as1, float* __restrict__ ad1)
{
    __shared__ float wsm[8 * 128];
    for (int i = threadIdx.x; i < 1024; i += 256) wsm[i] = wa1[i];
    __syncthreads();
    int n = blockIdx.x * 4 + (threadIdx.x >> 6);
    int l = threadIdx.x & 63;
    u32 xx = *(const u32*)(xb + (size_t)n * F1 + l * 2);
    float x0 = bf2f((u16)(xx & 0xffff)), x1 = bf2f((u16)(xx >> 16));
    float a[8];
    #pragma unroll
    for (int j = 0; j < 8; j++)
        a[j] = x0 * wsm[j * 128 + l * 2] + x1 * wsm[j * 128 + l * 2 + 1];
    #pragma unroll
    for (int off = 1; off < 64; off <<= 1) {
        #pragma unroll
        for (int j = 0; j < 8; j++) a[j] += __shfl_xor(a[j], off);
    }
    if (l == 0) {
        *(float4*)(as1 + (size_t)n * 4) = make_float4(a[0], a[1], a[2], a[3]);
        *(float4*)(ad1 + (size_t)n * 4) = make_float4(a[4], a[5], a[6], a[7]);
    }
}

// ---------------- logits layer 2: as2/ad2 = h2in(bf16) . wa2  (wa2 [256][2]) ----------------
__global__ __launch_bounds__(256) void k_logits2(
    const u16* __restrict__ h2in, const float* __restrict__ wa2,
    float* __restrict__ as2, float* __restrict__ ad2)
{
    int n = blockIdx.x * 4 + (threadIdx.x >> 6);
    int l = threadIdx.x & 63;
    ushort4 hv = *(const ushort4*)(h2in + (size_t)n * HC1 + l * 4);
    float4 wA = *(const float4*)(wa2 + l * 8);
    float4 wB = *(const float4*)(wa2 + l * 8 + 4);
    float h0 = bf2f(hv.x), h1 = bf2f(hv.y), h2 = bf2f(hv.z), h3 = bf2f(hv.w);
    float s2 = h0 * wA.x + h1 * wA.z + h2 * wB.x + h3 * wB.z;
    float d2 = h0 * wA.y + h1 * wA.w + h2 * wB.y + h3 * wB.w;
    #pragma unroll
    for (int off = 1; off < 64; off <<= 1) {
        s2 += __shfl_xor(s2, off);
        d2 += __shfl_xor(d2, off);
    }
    if (l == 0) { as2[n] = s2; ad2[n] = d2; }
}

// ---------------- P-pass: per-edge softmax numerators + per-node inverse denominator ----------------
template <int HEADS>
__global__ __launch_bounds__(256) void k_edgep(
    const int* __restrict__ row_ptr, const int* __restrict__ col,
    const float* __restrict__ as_, const float* __restrict__ ad_,
    float* __restrict__ pb, float* __restrict__ inv)
{
    int n = blockIdx.x * 4 + (threadIdx.x >> 6);
    const int lane = threadIdx.x & 63;
    int beg = row_ptr[n];
    int cnt = row_ptr[n + 1] - beg;
    if (HEADS == 4) {
        float4 ad4 = *(const float4*)(ad_ + (size_t)n * 4);
        float4 sp = make_float4(0.f, 0.f, 0.f, 0.f);
        for (int c = 0; c < cnt; c += 64) {
            int idx = c + lane;
            if (idx < cnt) {
                int e = beg + idx;
                int srcl = __builtin_nontemporal_load(col + e);
                float4 a4 = *(const float4*)(as_ + (size_t)srcl * 4);
                float t, p0, p1, p2, p3;
                t = a4.x + ad4.x; t = t > 0.f ? t : 0.2f * t; p0 = __expf(t);
                t = a4.y + ad4.y; t = t > 0.f ? t : 0.2f * t; p1 = __expf(t);
                t = a4.z + ad4.z; t = t > 0.f ? t : 0.2f * t; p2 = __expf(t);
                t = a4.w + ad4.w; t = t > 0.f ? t : 0.2f * t; p3 = __expf(t);
                pb[e] = p0; pb[NEA + e] = p1; pb[2 * NEA + e] = p2; pb[3 * NEA + e] = p3;
                sp.x += p0; sp.y += p1; sp.z += p2; sp.w += p3;
            }
        }
        #pragma unroll
        for (int off = 1; off < 64; off <<= 1) {
            sp.x += __shfl_xor(sp.x, off);
            sp.y += __shfl_xor(sp.y, off);
            sp.z += __shfl_xor(sp.z, off);
            sp.w += __shfl_xor(sp.w, off);
        }
        if (lane == 0)
            *(float4*)(inv + (size_t)n * 4) =
                make_float4(1.f / sp.x, 1.f / sp.y, 1.f / sp.z, 1.f / sp.w);
    } else {
        float ad0 = ad_[n];
        float sp = 0.f;
        for (int c = 0; c < cnt; c += 64) {
            int idx = c + lane;
            if (idx < cnt) {
                int e = beg + idx;
                int srcl = __builtin_nontemporal_load(col + e);
                float t = as_[srcl] + ad0;
                t = t > 0.f ? t : 0.2f * t;
                float p = __expf(t);
                pb[e] = p;
                sp += p;
            }
        }
        #pragma unroll
        for (int off = 1; off < 64; off <<= 1) sp += __shfl_xor(sp, off);
        if (lane == 0) inv[n] = 1.f / sp;
    }
}

// ---------------- G-pass: XCD-sliced gather-aggregate ----------------
// slice = blockIdx & (NSLICE-1): 32-channel slice, 3.2 MB table -> per-XCD L2 resident.
// FINAL=0: bf16 out + bias + ELU (h2in). FINAL=1: f32 out + bias (final output).
template <int NOUT, int NSLICE, int HEADS, int FINAL>
__global__ __launch_bounds__(256) void k_aggs(
    const int* __restrict__ row_ptr, const int* __restrict__ col, const u16* __restrict__ Hs,
    const float* __restrict__ pb, const float* __restrict__ inv,
    const float* __restrict__ bias, void* __restrict__ outp)
{
    __shared__ int   s_src[4][64];
    __shared__ float s_p[4][64];
    const int b = blockIdx.x;
    const int slice = b & (NSLICE - 1);
    const int nb = b / NSLICE;
    const int wv = threadIdx.x >> 6, lane = threadIdx.x & 63;
    const int n = nb * 4 + wv;
    const int head = (HEADS == 4) ? (slice >> 1) : 0;
    const int sub = lane >> 3, l8 = lane & 7;
    const u16* tab = Hs + (size_t)slice * NN * 32;
    const float* pbs = pb + (size_t)head * NEA;

    int beg = row_ptr[n];
    int cnt = row_ptr[n + 1] - beg;
    float a0 = 0.f, a1 = 0.f, a2 = 0.f, a3 = 0.f;
    for (int c = 0; c < cnt; c += 64) {
        int idx = c + lane;
        int srcl = 0;
        float p = 0.f;
        if (idx < cnt) {
            srcl = __builtin_nontemporal_load(col + beg + idx);
            p = __builtin_nontemporal_load(pbs + beg + idx);
        }
        s_src[wv][lane] = srcl;
        s_p[wv][lane] = p;
        int njit = (min(64, cnt - c) + 7) >> 3;
        for (int j = 0; j < njit; ++j) {
            int srcj = s_src[wv][j * 8 + sub];
            float pj = s_p[wv][j * 8 + sub];
            ushort4 hv = *(const ushort4*)(tab + (size_t)srcj * 32 + l8 * 4);
            a0 = fmaf(pj, bf2f(hv.x), a0);
            a1 = fmaf(pj, bf2f(hv.y), a1);
            a2 = fmaf(pj, bf2f(hv.z), a2);
            a3 = fmaf(pj, bf2f(hv.w), a3);
        }
    }
    #pragma unroll
    for (int off = 8; off <= 32; off <<= 1) {
        a0 += __shfl_xor(a0, off);
        a1 += __shfl_xor(a1, off);
        a2 += __shfl_xor(a2, off);
        a3 += __shfl_xor(a3, off);
    }
    if (lane < 8) {
        float iv = inv[(size_t)n * HEADS + head];
        int ch = slice * 32 + l8 * 4;
        float4 bv = *(const float4*)(bias + ch);
        float4 o;
        o.x = a0 * iv + bv.x;
        o.y = a1 * iv + bv.y;
        o.z = a2 * iv + bv.z;
        o.w = a3 * iv + bv.w;
        if (FINAL) {
            *(float4*)((float*)outp + (size_t)n * NOUT + ch) = o;
        } else {
            o.x = o.x > 0.f ? o.x : __expf(o.x) - 1.f;   // ELU
            o.y = o.y > 0.f ? o.y : __expf(o.y) - 1.f;
            o.z = o.z > 0.f ? o.z : __expf(o.z) - 1.f;
            o.w = o.w > 0.f ? o.w : __expf(o.w) - 1.f;
            ushort4 ob;
            ob.x = f2bf(o.x); ob.y = f2bf(o.y); ob.z = f2bf(o.z); ob.w = f2bf(o.w);
            *(ushort4*)((u16*)outp + (size_t)n * NOUT + ch) = ob;
        }
    }
}

// ---------------- launch ----------------
extern "C" void kernel_launch(void* const* d_in, const int* in_sizes, int n_in,
                              void* d_out, int out_size, void* d_ws, size_t ws_size,
                              hipStream_t stream) {
    const float* x   = (const float*)d_in[0];
    const int*       e32 = (const int*)d_in[1];
    const long long* e64 = (const long long*)d_in[1];
    const float* W1  = (const float*)d_in[2];
    const float* as1w = (const float*)d_in[3];
    const float* ad1w = (const float*)d_in[4];
    const float* b1  = (const float*)d_in[5];
    const float* W2  = (const float*)d_in[6];
    const float* as2w = (const float*)d_in[7];
    const float* ad2w = (const float*)d_in[8];
    const float* b2  = (const float*)d_in[9];
    float* out = (float*)d_out;

    char* w = (char*)d_ws;
    auto carve = [&](size_t bytes) -> void* {
        void* p = (void*)w;
        w += (bytes + 255) & ~(size_t)255;
        return p;
    };
    int*   flag    = (int*)carve(4);
    int*   row_ptr = (int*)carve((NN + 1) * sizeof(int));
    int*   cursor  = (int*)carve(NN * sizeof(int));
    int*   col     = (int*)carve((size_t)NEA * sizeof(int));
    int*   bsum    = (int*)carve(256 * sizeof(int));
    int*   boff    = (int*)carve(256 * sizeof(int));
    float* as1     = (float*)carve((size_t)NN * H1 * sizeof(float));
    float* ad1     = (float*)carve((size_t)NN * H1 * sizeof(float));
    float* as2     = (float*)carve((size_t)NN * sizeof(float));
    float* ad2     = (float*)carve((size_t)NN * sizeof(float));
    float* inv1    = (float*)carve((size_t)NN * H1 * sizeof(float));
    float* inv2    = (float*)carve((size_t)NN * sizeof(float));
    float* pb      = (float*)carve((size_t)4 * NEA * sizeof(float));
    u16*   xb      = (u16*)carve((size_t)NN * F1 * sizeof(u16));
    u16*   h1b     = (u16*)carve((size_t)NN * HC1 * sizeof(u16));   // sliced [8][NN][32]
    u16*   h2in    = (u16*)carve((size_t)NN * HC1 * sizeof(u16));   // linear (GEMM2 A)
    u16*   h2b     = (u16*)carve((size_t)NN * HC2 * sizeof(u16));   // sliced [4][NN][32]
    u16*   wp1     = (u16*)carve((size_t)F1 * HC1 * sizeof(u16));
    u16*   wp2     = (u16*)carve((size_t)HC1 * HC2 * sizeof(u16));
    float* wa1     = (float*)carve(8 * 128 * sizeof(float));
    float* wa2     = (float*)carve(256 * 2 * sizeof(float));

    const int TPB = 256;
    const int gN  = (NN + TPB - 1) / TPB;      // 196
    const int gE  = (NE + TPB - 1) / TPB;
    const int gM  = (NN + 63) / 64;            // 782
    const int gW  = NN / 4;                    // 12500

    k_prep<<<3382, 256, 0, stream>>>(x, W1, W2, as1w, ad1w, as2w, ad2w, xb, wp1, wp2, wa1, wa2);

    // CSR build (self-loops materialized)
    k_zero_detect<<<gN, TPB, 0, stream>>>(cursor, e32, flag);
    k_count<<<gE, TPB, 0, stream>>>(e32, e64, flag, cursor);
    k_part<<<gN, TPB, 0, stream>>>(cursor, bsum);
    k_scanb<<<1, 256, 0, stream>>>(bsum, boff, row_ptr, gN);
    k_addb<<<gN, TPB, 0, stream>>>(cursor, boff, row_ptr, cursor, col);
    k_fill<<<gE, TPB, 0, stream>>>(e32, e64, flag, cursor, col);

    // layer 1
    k_gemm_mfma<F1, HC1, 256><<<gM, 256, 0, stream>>>(xb, wp1, h1b, NN);
    k_logits1<<<gW, 256, 0, stream>>>(xb, wa1, as1, ad1);
    k_edgep<H1><<<gW, TPB, 0, stream>>>(row_ptr, col, as1, ad1, pb, inv1);
    k_aggs<HC1, 8, H1, 0><<<gW * 8, TPB, 0, stream>>>(row_ptr, col, h1b, pb, inv1, b1, h2in);

    // layer 2
    k_gemm_mfma<HC1, HC2, 128><<<gM, 128, 0, stream>>>(h2in, wp2, h2b, NN);
    k_logits2<<<gW, 256, 0, stream>>>(h2in, wa2, as2, ad2);
    k_edgep<1><<<gW, TPB, 0, stream>>>(row_ptr, col, as2, ad2, pb, inv2);
    k_aggs<HC2, 4, 1, 1><<<gW * 4, TPB, 0, stream>>>(row_ptr, col, h2b, pb, inv2, b2, out);
}

// Round 10
// 312.004 us; speedup vs baseline: 1.4773x; 1.4773x over previous
//
#include <hip/hip_runtime.h>

#define NN 50000
#define NE 800000

constexpr int H1 = 4, F1 = 128, HC1 = 256;
constexpr int HC2 = 128;

typedef unsigned short u16;
typedef unsigned int u32;
typedef __attribute__((ext_vector_type(8))) short bf16x8;
typedef __attribute__((ext_vector_type(4))) float f32x4;

__device__ __forceinline__ float bf2f(u16 h) {
    return __uint_as_float(((u32)h) << 16);
}
__device__ __forceinline__ u16 f2bf(float f) {
    u32 u = __float_as_uint(f);
    u32 r = (u + 0x7fffu + ((u >> 16) & 1u)) >> 16;   // RTN-even
    return (u16)r;
}

__device__ __forceinline__ int ld_edge(const int* e32, const long long* e64, int is64, long long idx) {
    return is64 ? (int)e64[idx] : e32[idx];
}

// ---------------- fused prep: x->bf16, W1/W2 pack, Wa = W @ att ----------------
__global__ __launch_bounds__(256) void k_prep(
    const float* __restrict__ x, const float* __restrict__ W1, const float* __restrict__ W2,
    const float* __restrict__ as1w, const float* __restrict__ ad1w,
    const float* __restrict__ as2w, const float* __restrict__ ad2w,
    u16* __restrict__ xb, u16* __restrict__ wp1, u16* __restrict__ wp2,
    float* __restrict__ wa1, float* __restrict__ wa2)
{
    const int b = blockIdx.x, tid = threadIdx.x;
    if (b < 3125) {                       // cvt: 3125*256*8 == NN*F1
        int i = b * 256 + tid;
        const float4* p = (const float4*)x + (size_t)i * 2;
        float4 a = p[0], c = p[1];
        ushort4 o0, o1;
        o0.x = f2bf(a.x); o0.y = f2bf(a.y); o0.z = f2bf(a.z); o0.w = f2bf(a.w);
        o1.x = f2bf(c.x); o1.y = f2bf(c.y); o1.z = f2bf(c.z); o1.w = f2bf(c.w);
        ((ushort4*)xb)[(size_t)i * 2] = o0;
        ((ushort4*)xb)[(size_t)i * 2 + 1] = o1;
    } else if (b < 3253) {                // wp1: [NK][256][4][8] <- W1[128][256]
        int o = (b - 3125) * 256 + tid;
        int j = o & 7, lk = (o >> 3) & 3, nn = (o >> 5) & 255, kc = o >> 13;
        int k = kc * 32 + lk * 8 + j;
        wp1[o] = f2bf(W1[(size_t)k * HC1 + nn]);
    } else if (b < 3381) {                // wp2: [NK][128][4][8] <- W2[256][128]
        int o = (b - 3253) * 256 + tid;
        int j = o & 7, lk = (o >> 3) & 3, nn = (o >> 5) & 127, kc = o >> 12;
        int k = kc * 32 + lk * 8 + j;
        wp2[o] = f2bf(W2[(size_t)k * HC2 + nn]);
    } else {                              // watt
        #pragma unroll
        for (int pp = 0; pp < 2; pp++) {
            int p = tid + pp * 256;       // 512 (k,h) pairs
            int k = p >> 2, h = p & 3;
            float s = 0.f, d = 0.f;
            for (int c = 0; c < 64; c++) {
                float wv = W1[(size_t)k * HC1 + h * 64 + c];
                s = fmaf(wv, as1w[h * 64 + c], s);
                d = fmaf(wv, ad1w[h * 64 + c], d);
            }
            wa1[h * 128 + k] = s;
            wa1[(4 + h) * 128 + k] = d;
        }
        {   // wa2 [256][2]
            int k = tid;
            float s = 0.f, d = 0.f;
            for (int c = 0; c < 128; c++) {
                float wv = W2[(size_t)k * HC2 + c];
                s = fmaf(wv, as2w[c], s);
                d = fmaf(wv, ad2w[c], d);
            }
            wa2[k * 2] = s;
            wa2[k * 2 + 1] = d;
        }
    }
}

// ---------------- CSR build (self-loops materialized at slot 0 of each row) ----------------
__global__ void k_zero_detect(int* __restrict__ p, const int* __restrict__ e32, int* __restrict__ flag) {
    int i = blockIdx.x * blockDim.x + threadIdx.x;
    if (i < NN) p[i] = 1;                 // degree starts at 1: self-loop
    if (i == 0) {
        int z = 1;
        for (int t = 0; t < 16; t++)
            if (e32[2 * t + 1] != 0) z = 0;
        *flag = z;
    }
}

__global__ void k_count(const int* __restrict__ e32, const long long* __restrict__ e64,
                        const int* __restrict__ flag, int* __restrict__ deg) {
    int e = blockIdx.x * blockDim.x + threadIdx.x;
    if (e >= NE) return;
    int is64 = *flag;
    int dst = ld_edge(e32, e64, is64, (long long)NE + e);
    atomicAdd(&deg[dst], 1);
}

__global__ __launch_bounds__(256) void k_part(const int* __restrict__ deg, int* __restrict__ bsum) {
    int i = blockIdx.x * 256 + threadIdx.x;
    int v = (i < NN) ? deg[i] : 0;
    #pragma unroll
    for (int off = 1; off < 64; off <<= 1) v += __shfl_xor(v, off);
    __shared__ int ws[4];
    if ((threadIdx.x & 63) == 0) ws[threadIdx.x >> 6] = v;
    __syncthreads();
    if (threadIdx.x == 0) bsum[blockIdx.x] = ws[0] + ws[1] + ws[2] + ws[3];
}

__global__ __launch_bounds__(256) void k_scanb(const int* __restrict__ bsum, int* __restrict__ boff,
                                               int* __restrict__ row_ptr, int NB) {
    const int tid = threadIdx.x;
    const int lane = tid & 63, wv = tid >> 6;
    int v = (tid < NB) ? bsum[tid] : 0;
    int x = v;
    #pragma unroll
    for (int off = 1; off < 64; off <<= 1) {
        int t = __shfl_up(x, off);
        if (lane >= off) x += t;
    }
    __shared__ int wsum[4], woff[4];
    if (lane == 63) wsum[wv] = x;
    __syncthreads();
    if (tid == 0) {
        int run = 0;
        #pragma unroll
        for (int j = 0; j < 4; j++) { woff[j] = run; run += wsum[j]; }
        row_ptr[NN] = run;
    }
    __syncthreads();
    if (tid < NB) boff[tid] = x - v + woff[wv];
}

__global__ __launch_bounds__(256) void k_addb(const int* __restrict__ deg, const int* __restrict__ boff,
                                              int* __restrict__ row_ptr, int* __restrict__ cursor,
                                              int* __restrict__ col) {
    const int tid = threadIdx.x;
    const int lane = tid & 63, wv = tid >> 6;
    int i = blockIdx.x * 256 + tid;
    int v = (i < NN) ? deg[i] : 0;
    int x = v;
    #pragma unroll
    for (int off = 1; off < 64; off <<= 1) {
        int t = __shfl_up(x, off);
        if (lane >= off) x += t;
    }
    __shared__ int wsum[4], woff[4];
    if (lane == 63) wsum[wv] = x;
    __syncthreads();
    if (tid == 0) {
        int run = 0;
        #pragma unroll
        for (int j = 0; j < 4; j++) { woff[j] = run; run += wsum[j]; }
    }
    __syncthreads();
    int excl = x - v + woff[wv] + boff[blockIdx.x];
    if (i < NN) {
        row_ptr[i] = excl;
        cursor[i] = excl + 1;    // slot 0 reserved for self-loop
        col[excl] = i;
    }
}

__global__ void k_fill(const int* __restrict__ e32, const long long* __restrict__ e64,
                       const int* __restrict__ flag, int* __restrict__ cursor, int* __restrict__ col) {
    int e = blockIdx.x * blockDim.x + threadIdx.x;
    if (e >= NE) return;
    int is64 = *flag;
    int src = ld_edge(e32, e64, is64, e);
    int dst = ld_edge(e32, e64, is64, (long long)NE + e);
    int pos = atomicAdd(&cursor[dst], 1);
    col[pos] = src;
}

// ---------------- pure MFMA GEMM (linear H output) ----------------
template <int K, int NOUT, int TPB>
__global__ __launch_bounds__(TPB) void k_gemm_mfma(
    const u16* __restrict__ Ab, const u16* __restrict__ Wp, u16* __restrict__ Hout, int M)
{
    constexpr int BM = 64, BK = 32;
    constexpr int NK = K / BK;
    constexpr int LDA = 40;
    __shared__ __align__(16) u16 As[2][BM * LDA];

    const int tid = threadIdx.x;
    const int w = tid >> 6;
    const int l = tid & 63;
    const int l15 = l & 15, lk = l >> 4;
    const int row0 = blockIdx.x * BM;
    const int col0 = w * 64;

    f32x4 acc[4][4];
    #pragma unroll
    for (int rt = 0; rt < 4; rt++)
        #pragma unroll
        for (int nt = 0; nt < 4; nt++)
            acc[rt][nt] = (f32x4){0.f, 0.f, 0.f, 0.f};

    auto stage = [&](int kc, int b) {
        #pragma unroll
        for (int i = tid; i < BM * 4; i += TPB) {
            int r = i >> 2, c = (i & 3) * 8;
            int gr = row0 + r;
            bf16x8 v = {0, 0, 0, 0, 0, 0, 0, 0};
            if (gr < M) v = *(const bf16x8*)(Ab + (size_t)gr * K + kc * BK + c);
            *(bf16x8*)&As[b][r * LDA + c] = v;
        }
    };
    auto loadB = [&](int kc, bf16x8* bf) {
        #pragma unroll
        for (int nt = 0; nt < 4; nt++)
            bf[nt] = *(const bf16x8*)(Wp + (((size_t)kc * NOUT + col0 + nt * 16 + l15) * 4 + lk) * 8);
    };

    bf16x8 bcur[4];
    loadB(0, bcur);
    stage(0, 0);
    for (int kc = 0; kc < NK; ++kc) {
        __syncthreads();
        bf16x8 afr[4];
        #pragma unroll
        for (int rt = 0; rt < 4; rt++)
            afr[rt] = *(const bf16x8*)&As[kc & 1][(rt * 16 + l15) * LDA + lk * 8];
        bf16x8 bnext[4];
        if (kc + 1 < NK) {
            loadB(kc + 1, bnext);
            stage(kc + 1, (kc + 1) & 1);
        }
        #pragma unroll
        for (int rt = 0; rt < 4; rt++)
            #pragma unroll
            for (int nt = 0; nt < 4; nt++)
                acc[rt][nt] = __builtin_amdgcn_mfma_f32_16x16x32_bf16(afr[rt], bcur[nt], acc[rt][nt], 0, 0, 0);
        if (kc + 1 < NK) {
            #pragma unroll
            for (int nt = 0; nt < 4; nt++) bcur[nt] = bnext[nt];
        }
    }

    // D layout col=l&15, row=(l>>4)*4+t  [m89-verified]
    #pragma unroll
    for (int rt = 0; rt < 4; rt++) {
        #pragma unroll
        for (int t = 0; t < 4; t++) {
            int gr = row0 + rt * 16 + lk * 4 + t;
            if (gr < M) {
                #pragma unroll
                for (int nt = 0; nt < 4; nt++)
                    Hout[(size_t)gr * NOUT + col0 + nt * 16 + l15] = f2bf(acc[rt][nt][t]);
            }
        }
    }
}

// ---------------- logits layer 1: as1/ad1 = xb @ Wa1  (Wa1 [8][128]) ----------------
__global__ __launch_bounds__(256) void k_logits1(
    const u16* __restrict__ xb, const float* __restrict__ wa1,
    float* __restrict__ as1, float* __restrict__ ad1)
{
    __shared__ float wsm[8 * 128];
    for (int i = threadIdx.x; i < 1024; i += 256) wsm[i] = wa1[i];
    __syncthreads();
    int n = blockIdx.x * 4 + (threadIdx.x >> 6);
    int l = threadIdx.x & 63;
    u32 xx = *(const u32*)(xb + (size_t)n * F1 + l * 2);
    float x0 = bf2f((u16)(xx & 0xffff)), x1 = bf2f((u16)(xx >> 16));
    float a[8];
    #pragma unroll
    for (int j = 0; j < 8; j++)
        a[j] = x0 * wsm[j * 128 + l * 2] + x1 * wsm[j * 128 + l * 2 + 1];
    #pragma unroll
    for (int off = 1; off < 64; off <<= 1) {
        #pragma unroll
        for (int j = 0; j < 8; j++) a[j] += __shfl_xor(a[j], off);
    }
    if (l == 0) {
        *(float4*)(as1 + (size_t)n * 4) = make_float4(a[0], a[1], a[2], a[3]);
        *(float4*)(ad1 + (size_t)n * 4) = make_float4(a[4], a[5], a[6], a[7]);
    }
}

// ---------------- aggregation layer 1 + fused layer-2 logits ----------------
__global__ __launch_bounds__(256) void k_agg1(
    const int* __restrict__ row_ptr, const int* __restrict__ col,
    const u16* __restrict__ Hb, const float* __restrict__ as_, const float* __restrict__ ad_,
    const float* __restrict__ bias, const float* __restrict__ wa2,
    u16* __restrict__ outp, float* __restrict__ as2, float* __restrict__ ad2)
{
    __shared__ int    s_src[4][64];
    __shared__ float4 s_p[4][64];
    int n = blockIdx.x * 4 + (threadIdx.x >> 6);
    const int lane = threadIdx.x & 63;
    const int wv = threadIdx.x >> 6;
    const int head = lane >> 4;
    float4 ad4 = *(const float4*)(ad_ + (size_t)n * 4);
    int beg = row_ptr[n];
    int cnt = row_ptr[n + 1] - beg;       // self-loop at slot 0
    float4 sp = make_float4(0.f, 0.f, 0.f, 0.f);
    float ax = 0.f, ay = 0.f, az = 0.f, aw = 0.f;
    for (int c = 0; c < cnt; c += 64) {
        int idx = c + lane;
        int srcl = 0;
        float4 p4 = make_float4(0.f, 0.f, 0.f, 0.f);
        if (idx < cnt) {
            srcl = __builtin_nontemporal_load(col + beg + idx);
            float4 a4 = *(const float4*)(as_ + (size_t)srcl * 4);
            float e;
            e = a4.x + ad4.x; e = e > 0.f ? e : 0.2f * e; p4.x = __expf(e);
            e = a4.y + ad4.y; e = e > 0.f ? e : 0.2f * e; p4.y = __expf(e);
            e = a4.z + ad4.z; e = e > 0.f ? e : 0.2f * e; p4.z = __expf(e);
            e = a4.w + ad4.w; e = e > 0.f ? e : 0.2f * e; p4.w = __expf(e);
        }
        sp.x += p4.x; sp.y += p4.y; sp.z += p4.z; sp.w += p4.w;
        s_src[wv][lane] = srcl;
        s_p[wv][lane] = p4;
        int jmax = min(64, cnt - c);
        #pragma unroll 4
        for (int j = 0; j < jmax; ++j) {
            // row index is wave-uniform: hoist to SGPR so the address math is scalar
            int srcj = __builtin_amdgcn_readfirstlane(s_src[wv][j]);
            float pj = ((const float*)&s_p[wv][j])[head];
            ushort4 hv = *(const ushort4*)(Hb + (size_t)srcj * HC1 + lane * 4);
            ax = fmaf(pj, bf2f(hv.x), ax);
            ay = fmaf(pj, bf2f(hv.y), ay);
            az = fmaf(pj, bf2f(hv.z), az);
            aw = fmaf(pj, bf2f(hv.w), aw);
        }
    }
    #pragma unroll
    for (int off = 1; off < 64; off <<= 1) {
        sp.x += __shfl_xor(sp.x, off);
        sp.y += __shfl_xor(sp.y, off);
        sp.z += __shfl_xor(sp.z, off);
        sp.w += __shfl_xor(sp.w, off);
    }
    float s = head < 2 ? (head == 0 ? sp.x : sp.y) : (head == 2 ? sp.z : sp.w);
    float inv = 1.f / s;
    float4 bv = *(const float4*)(bias + lane * 4);
    float4 o;
    o.x = ax * inv + bv.x;
    o.y = ay * inv + bv.y;
    o.z = az * inv + bv.z;
    o.w = aw * inv + bv.w;
    o.x = o.x > 0.f ? o.x : __expf(o.x) - 1.f;   // ELU
    o.y = o.y > 0.f ? o.y : __expf(o.y) - 1.f;
    o.z = o.z > 0.f ? o.z : __expf(o.z) - 1.f;
    o.w = o.w > 0.f ? o.w : __expf(o.w) - 1.f;
    ushort4 ob;
    ob.x = f2bf(o.x); ob.y = f2bf(o.y); ob.z = f2bf(o.z); ob.w = f2bf(o.w);
    *(ushort4*)(outp + (size_t)n * HC1 + lane * 4) = ob;

    // fused layer-2 logits: as2[n] = o . Wa2_s, ad2[n] = o . Wa2_d  (wa2 [256][2])
    float4 wA = *(const float4*)(wa2 + lane * 8);
    float4 wB = *(const float4*)(wa2 + lane * 8 + 4);
    float s2 = o.x * wA.x + o.y * wA.z + o.z * wB.x + o.w * wB.z;
    float d2 = o.x * wA.y + o.y * wA.w + o.z * wB.y + o.w * wB.w;
    #pragma unroll
    for (int off = 1; off < 64; off <<= 1) {
        s2 += __shfl_xor(s2, off);
        d2 += __shfl_xor(d2, off);
    }
    if (lane == 0) { as2[n] = s2; ad2[n] = d2; }
}

// ---------------- aggregation layer 2 ----------------
__global__ __launch_bounds__(256) void k_agg2(
    const int* __restrict__ row_ptr, const int* __restrict__ col,
    const u16* __restrict__ Hb, const float* __restrict__ as_, const float* __restrict__ ad_,
    const float* __restrict__ bias, float* __restrict__ outp)
{
    __shared__ int   s_src[4][64];
    __shared__ float s_p[4][64];
    int n = blockIdx.x * 4 + (threadIdx.x >> 6);
    const int lane = threadIdx.x & 63;
    const int wv = threadIdx.x >> 6;
    float ad0 = ad_[n];
    int beg = row_ptr[n];
    int cnt = row_ptr[n + 1] - beg;
    float sp = 0.f;
    float ax = 0.f, ay = 0.f;
    for (int c = 0; c < cnt; c += 64) {
        int idx = c + lane;
        int srcl = 0;
        float p = 0.f;
        if (idx < cnt) {
            srcl = __builtin_nontemporal_load(col + beg + idx);
            float e = as_[srcl] + ad0;
            e = e > 0.f ? e : 0.2f * e;
            p = __expf(e);
        }
        sp += p;
        s_src[wv][lane] = srcl;
        s_p[wv][lane] = p;
        int jmax = min(64, cnt - c);
        #pragma unroll 4
        for (int j = 0; j < jmax; ++j) {
            // both row index and weight are wave-uniform -> scalar regs
            int srcj = __builtin_amdgcn_readfirstlane(s_src[wv][j]);
            float pj = __uint_as_float(__builtin_amdgcn_readfirstlane(__float_as_uint(s_p[wv][j])));
            ushort2 hv = *(const ushort2*)(Hb + (size_t)srcj * HC2 + lane * 2);
            ax = fmaf(pj, bf2f(hv.x), ax);
            ay = fmaf(pj, bf2f(hv.y), ay);
        }
    }
    #pragma unroll
    for (int off = 1; off < 64; off <<= 1) sp += __shfl_xor(sp, off);
    float inv = 1.f / sp;
    float2 bv = *(const float2*)(bias + lane * 2);
    float2 o = make_float2(ax * inv + bv.x, ay * inv + bv.y);
    *(float2*)(outp + (size_t)n * HC2 + lane * 2) = o;
}

// ---------------- launch ----------------
extern "C" void kernel_launch(void* const* d_in, const int* in_sizes, int n_in,
                              void* d_out, int out_size, void* d_ws, size_t ws_size,
                              hipStream_t stream) {
    const float* x   = (const float*)d_in[0];
    const int*       e32 = (const int*)d_in[1];
    const long long* e64 = (const long long*)d_in[1];
    const float* W1  = (const float*)d_in[2];
    const float* as1w = (const float*)d_in[3];
    const float* ad1w = (const float*)d_in[4];
    const float* b1  = (const float*)d_in[5];
    const float* W2  = (const float*)d_in[6];
    const float* as2w = (const float*)d_in[7];
    const float* ad2w = (const float*)d_in[8];
    const float* b2  = (const float*)d_in[9];
    float* out = (float*)d_out;

    char* w = (char*)d_ws;
    auto carve = [&](size_t bytes) -> void* {
        void* p = (void*)w;
        w += (bytes + 255) & ~(size_t)255;
        return p;
    };
    int*   flag    = (int*)carve(4);
    int*   row_ptr = (int*)carve((NN + 1) * sizeof(int));
    int*   cursor  = (int*)carve(NN * sizeof(int));
    int*   col     = (int*)carve((size_t)(NE + NN) * sizeof(int));
    int*   bsum    = (int*)carve(256 * sizeof(int));
    int*   boff    = (int*)carve(256 * sizeof(int));
    float* as1     = (float*)carve((size_t)NN * H1 * sizeof(float));
    float* ad1     = (float*)carve((size_t)NN * H1 * sizeof(float));
    float* as2     = (float*)carve((size_t)NN * sizeof(float));
    float* ad2     = (float*)carve((size_t)NN * sizeof(float));
    u16*   xb      = (u16*)carve((size_t)NN * F1 * sizeof(u16));
    u16*   h1b     = (u16*)carve((size_t)NN * HC1 * sizeof(u16));
    u16*   h2in    = (u16*)carve((size_t)NN * HC1 * sizeof(u16));
    u16*   h2b     = (u16*)carve((size_t)NN * HC2 * sizeof(u16));
    u16*   wp1     = (u16*)carve((size_t)F1 * HC1 * sizeof(u16));
    u16*   wp2     = (u16*)carve((size_t)HC1 * HC2 * sizeof(u16));
    float* wa1     = (float*)carve(8 * 128 * sizeof(float));
    float* wa2     = (float*)carve(256 * 2 * sizeof(float));

    const int TPB = 256;
    const int gN  = (NN + TPB - 1) / TPB;      // 196
    const int gE  = (NE + TPB - 1) / TPB;
    const int gM  = (NN + 63) / 64;            // 782
    const int gW  = NN / 4;                    // 12500

    k_prep<<<3382, 256, 0, stream>>>(x, W1, W2, as1w, ad1w, as2w, ad2w, xb, wp1, wp2, wa1, wa2);

    // CSR build (self-loops materialized)
    k_zero_detect<<<gN, TPB, 0, stream>>>(cursor, e32, flag);
    k_count<<<gE, TPB, 0, stream>>>(e32, e64, flag, cursor);
    k_part<<<gN, TPB, 0, stream>>>(cursor, bsum);
    k_scanb<<<1, 256, 0, stream>>>(bsum, boff, row_ptr, gN);
    k_addb<<<gN, TPB, 0, stream>>>(cursor, boff, row_ptr, cursor, col);
    k_fill<<<gE, TPB, 0, stream>>>(e32, e64, flag, cursor, col);

    // layer 1
    k_gemm_mfma<F1, HC1, 256><<<gM, 256, 0, stream>>>(xb, wp1, h1b, NN);
    k_logits1<<<gW, 256, 0, stream>>>(xb, wa1, as1, ad1);
    k_agg1<<<gW, TPB, 0, stream>>>(row_ptr, col, h1b, as1, ad1, b1, wa2, h2in, as2, ad2);

    // layer 2
    k_gemm_mfma<HC1, HC2, 128><<<gM, 128, 0, stream>>>(h2in, wp2, h2b, NN);
    k_agg2<<<gW, TPB, 0, stream>>>(row_ptr, col, h2b, as2, ad2, b2, out);
}

// Round 11
// 240.886 us; speedup vs baseline: 1.9135x; 1.2952x over previous
//
#include <hip/hip_runtime.h>

#define NN 50000
#define NE 800000

constexpr int H1 = 4, F1 = 128, HC1 = 256;
constexpr int HC2 = 128;

typedef unsigned short u16;
typedef unsigned int u32;
typedef __attribute__((ext_vector_type(8))) short bf16x8;
typedef __attribute__((ext_vector_type(4))) float f32x4;

__device__ __forceinline__ float bf2f(u16 h) {
    return __uint_as_float(((u32)h) << 16);
}
__device__ __forceinline__ u16 f2bf(float f) {
    u32 u = __float_as_uint(f);
    u32 r = (u + 0x7fffu + ((u >> 16) & 1u)) >> 16;   // RTN-even
    return (u16)r;
}

// ---------------- edge index access (int32 vs int64 hedge) ----------------
__device__ __forceinline__ int ld_edge(const int* e32, const long long* e64, int is64, long long idx) {
    return is64 ? (int)e64[idx] : e32[idx];
}

// ---------------- x -> bf16 ----------------
__global__ __launch_bounds__(256) void k_cvt(const float* __restrict__ in, u16* __restrict__ out, int n8) {
    int i = blockIdx.x * 256 + threadIdx.x;
    if (i >= n8) return;
    const float4* p = (const float4*)in + (size_t)i * 2;
    float4 a = p[0], b = p[1];
    ushort4 o0, o1;
    o0.x = f2bf(a.x); o0.y = f2bf(a.y); o0.z = f2bf(a.z); o0.w = f2bf(a.w);
    o1.x = f2bf(b.x); o1.y = f2bf(b.y); o1.z = f2bf(b.z); o1.w = f2bf(b.w);
    ((ushort4*)out)[(size_t)i * 2] = o0;
    ((ushort4*)out)[(size_t)i * 2 + 1] = o1;
}

// ---------------- CSR build ----------------
__global__ void k_zero_detect(int* __restrict__ p, const int* __restrict__ e32, int* __restrict__ flag) {
    int i = blockIdx.x * blockDim.x + threadIdx.x;
    if (i < NN) p[i] = 0;
    if (i == 0) {
        int z = 1;
        for (int t = 0; t < 16; t++)
            if (e32[2 * t + 1] != 0) z = 0;   // int64 little-endian high words
        *flag = z;
    }
}

__global__ void k_count(const int* __restrict__ e32, const long long* __restrict__ e64,
                        const int* __restrict__ flag, int* __restrict__ deg) {
    int e = blockIdx.x * blockDim.x + threadIdx.x;
    if (e >= NE) return;
    int is64 = *flag;
    int dst = ld_edge(e32, e64, is64, (long long)NE + e);
    atomicAdd(&deg[dst], 1);
}

// phase 1: per-block (256) sums
__global__ __launch_bounds__(256) void k_part(const int* __restrict__ deg, int* __restrict__ bsum) {
    int i = blockIdx.x * 256 + threadIdx.x;
    int v = (i < NN) ? deg[i] : 0;
    #pragma unroll
    for (int off = 1; off < 64; off <<= 1) v += __shfl_xor(v, off);
    __shared__ int ws[4];
    if ((threadIdx.x & 63) == 0) ws[threadIdx.x >> 6] = v;
    __syncthreads();
    if (threadIdx.x == 0) bsum[blockIdx.x] = ws[0] + ws[1] + ws[2] + ws[3];
}

// phase 2: single block scans NB block sums (NB <= 256)
__global__ __launch_bounds__(256) void k_scanb(const int* __restrict__ bsum, int* __restrict__ boff,
                                               int* __restrict__ row_ptr, int NB) {
    const int tid = threadIdx.x;
    const int lane = tid & 63, wv = tid >> 6;
    int v = (tid < NB) ? bsum[tid] : 0;
    int x = v;
    #pragma unroll
    for (int off = 1; off < 64; off <<= 1) {
        int t = __shfl_up(x, off);
        if (lane >= off) x += t;
    }
    __shared__ int wsum[4], woff[4];
    if (lane == 63) wsum[wv] = x;
    __syncthreads();
    if (tid == 0) {
        int run = 0;
        #pragma unroll
        for (int j = 0; j < 4; j++) { woff[j] = run; run += wsum[j]; }
        row_ptr[NN] = run;
    }
    __syncthreads();
    if (tid < NB) boff[tid] = x - v + woff[wv];
}

// phase 3: per-block exclusive scan + block offset -> row_ptr, cursor
__global__ __launch_bounds__(256) void k_addb(const int* __restrict__ deg, const int* __restrict__ boff,
                                              int* __restrict__ row_ptr, int* __restrict__ cursor) {
    const int tid = threadIdx.x;
    const int lane = tid & 63, wv = tid >> 6;
    int i = blockIdx.x * 256 + tid;
    int v = (i < NN) ? deg[i] : 0;
    int x = v;
    #pragma unroll
    for (int off = 1; off < 64; off <<= 1) {
        int t = __shfl_up(x, off);
        if (lane >= off) x += t;
    }
    __shared__ int wsum[4], woff[4];
    if (lane == 63) wsum[wv] = x;
    __syncthreads();
    if (tid == 0) {
        int run = 0;
        #pragma unroll
        for (int j = 0; j < 4; j++) { woff[j] = run; run += wsum[j]; }
    }
    __syncthreads();
    int excl = x - v + woff[wv] + boff[blockIdx.x];
    if (i < NN) { row_ptr[i] = excl; cursor[i] = excl; }
}

__global__ void k_fill(const int* __restrict__ e32, const long long* __restrict__ e64,
                       const int* __restrict__ flag, int* __restrict__ cursor, int* __restrict__ col) {
    int e = blockIdx.x * blockDim.x + threadIdx.x;
    if (e >= NE) return;
    int is64 = *flag;
    int src = ld_edge(e32, e64, is64, e);
    int dst = ld_edge(e32, e64, is64, (long long)NE + e);
    int pos = atomicAdd(&cursor[dst], 1);
    col[pos] = src;
}

// ---------------- W prep: W[K][N] f32 -> MFMA-fragment-packed bf16 ----------------
// Wp layout: [NK][N][4][8];  Wp[((kc*N + n)*4 + lk)*8 + j] = W[(kc*32 + lk*8 + j)*N + n]
template <int K, int N>
__global__ __launch_bounds__(256) void k_prepw(const float* __restrict__ W, u16* __restrict__ Wp) {
    constexpr int LGN = (N == 256) ? 8 : 7;
    int o = blockIdx.x * 256 + threadIdx.x;
    if (o >= K * N) return;
    int j = o & 7;
    int lk = (o >> 3) & 3;
    int nn = (o >> 5) & (N - 1);
    int kc = o >> (5 + LGN);
    int k = kc * 32 + lk * 8 + j;
    Wp[o] = f2bf(W[(size_t)k * N + nn]);
}

// ---------------- MFMA GEMM + attention-logit epilogue ----------------
template <int K, int NOUT, int HEADS, int TPB>
__global__ __launch_bounds__(TPB) void k_gemm_mfma(
    const u16* __restrict__ Ab, const u16* __restrict__ Wp,
    const float* __restrict__ atts, const float* __restrict__ attd,
    u16* __restrict__ Hout, float* __restrict__ as_out, float* __restrict__ ad_out, int M)
{
    constexpr int BM = 64, BK = 32;
    constexpr int NK = K / BK;
    constexpr int C = NOUT / HEADS;
    constexpr int LDA = 40;                         // u16 per LDS row (80 B padded)
    __shared__ __align__(16) u16 As[2][BM * LDA];
    __shared__ float red_s[BM * HEADS];
    __shared__ float red_d[BM * HEADS];

    const int tid = threadIdx.x;
    const int w = tid >> 6;
    const int l = tid & 63;
    const int l15 = l & 15, lk = l >> 4;
    const int row0 = blockIdx.x * BM;
    const int col0 = w * 64;

    for (int i = tid; i < BM * HEADS; i += TPB) { red_s[i] = 0.f; red_d[i] = 0.f; }

    f32x4 acc[4][4];
    #pragma unroll
    for (int rt = 0; rt < 4; rt++)
        #pragma unroll
        for (int nt = 0; nt < 4; nt++)
            acc[rt][nt] = (f32x4){0.f, 0.f, 0.f, 0.f};

    auto stage = [&](int kc, int b) {
        #pragma unroll
        for (int i = tid; i < BM * 4; i += TPB) {
            int r = i >> 2, c = (i & 3) * 8;
            int gr = row0 + r;
            bf16x8 v = {0, 0, 0, 0, 0, 0, 0, 0};
            if (gr < M) v = *(const bf16x8*)(Ab + (size_t)gr * K + kc * BK + c);
            *(bf16x8*)&As[b][r * LDA + c] = v;
        }
    };
    auto loadB = [&](int kc, bf16x8* bf) {
        #pragma unroll
        for (int nt = 0; nt < 4; nt++)
            bf[nt] = *(const bf16x8*)(Wp + (((size_t)kc * NOUT + col0 + nt * 16 + l15) * 4 + lk) * 8);
    };

    bf16x8 bcur[4];
    loadB(0, bcur);
    stage(0, 0);
    for (int kc = 0; kc < NK; ++kc) {
        __syncthreads();
        bf16x8 afr[4];
        #pragma unroll
        for (int rt = 0; rt < 4; rt++)
            afr[rt] = *(const bf16x8*)&As[kc & 1][(rt * 16 + l15) * LDA + lk * 8];
        bf16x8 bnext[4];
        if (kc + 1 < NK) {
            loadB(kc + 1, bnext);
            stage(kc + 1, (kc + 1) & 1);
        }
        #pragma unroll
        for (int rt = 0; rt < 4; rt++)
            #pragma unroll
            for (int nt = 0; nt < 4; nt++)
                acc[rt][nt] = __builtin_amdgcn_mfma_f32_16x16x32_bf16(afr[rt], bcur[nt], acc[rt][nt], 0, 0, 0);
        if (kc + 1 < NK) {
            #pragma unroll
            for (int nt = 0; nt < 4; nt++) bcur[nt] = bnext[nt];
        }
    }

    // ---- write H (bf16): D layout col=l&15, row=(l>>4)*4+t  [m89-verified] ----
    #pragma unroll
    for (int rt = 0; rt < 4; rt++) {
        #pragma unroll
        for (int t = 0; t < 4; t++) {
            int gr = row0 + rt * 16 + lk * 4 + t;
            if (gr < M) {
                #pragma unroll
                for (int nt = 0; nt < 4; nt++)
                    Hout[(size_t)gr * NOUT + col0 + nt * 16 + l15] = f2bf(acc[rt][nt][t]);
            }
        }
    }

    // ---- attention logits ----
    float avs[4], avd[4];
    #pragma unroll
    for (int nt = 0; nt < 4; nt++) {
        int gc = col0 + nt * 16 + l15;
        avs[nt] = atts[gc];
        avd[nt] = attd[gc];
    }
    const int headw = col0 / C;
    #pragma unroll
    for (int rt = 0; rt < 4; rt++) {
        #pragma unroll
        for (int t = 0; t < 4; t++) {
            float ps = 0.f, pd = 0.f;
            #pragma unroll
            for (int nt = 0; nt < 4; nt++) {
                ps = fmaf(acc[rt][nt][t], avs[nt], ps);
                pd = fmaf(acc[rt][nt][t], avd[nt], pd);
            }
            ps += __shfl_xor(ps, 1); ps += __shfl_xor(ps, 2);
            ps += __shfl_xor(ps, 4); ps += __shfl_xor(ps, 8);
            pd += __shfl_xor(pd, 1); pd += __shfl_xor(pd, 2);
            pd += __shfl_xor(pd, 4); pd += __shfl_xor(pd, 8);
            if (l15 == 0) {
                int row = rt * 16 + lk * 4 + t;
                atomicAdd(&red_s[row * HEADS + headw], ps);
                atomicAdd(&red_d[row * HEADS + headw], pd);
            }
        }
    }
    __syncthreads();
    for (int i = tid; i < BM * HEADS; i += TPB) {
        int gr = row0 + i / HEADS;
        if (gr < M) {
            as_out[(size_t)gr * HEADS + i % HEADS] = red_s[i];
            ad_out[(size_t)gr * HEADS + i % HEADS] = red_d[i];
        }
    }
}

// ---------------- aggregation layer 1: wave/dst, LDS (src,p) staging, bf16 gather ----------------
__global__ __launch_bounds__(256) void k_agg1(
    const int* __restrict__ row_ptr, const int* __restrict__ col,
    const u16* __restrict__ Hb, const float* __restrict__ as_, const float* __restrict__ ad_,
    const float* __restrict__ bias, u16* __restrict__ outp)
{
    __shared__ int    s_src[4][64];
    __shared__ float4 s_p[4][64];
    int n = blockIdx.x * 4 + (threadIdx.x >> 6);
    if (n >= NN) return;
    const int lane = threadIdx.x & 63;
    const int wv = threadIdx.x >> 6;
    const int head = lane >> 4;                 // channels lane*4..lane*4+3 live in head lane>>4
    float4 ad4 = *(const float4*)(ad_ + (size_t)n * 4);
    int beg = row_ptr[n];
    int cnt = row_ptr[n + 1] - beg + 1;         // +1: self loop first
    float4 sp = make_float4(0.f, 0.f, 0.f, 0.f);
    float ax = 0.f, ay = 0.f, az = 0.f, aw = 0.f;
    for (int c = 0; c < cnt; c += 64) {
        int idx = c + lane;
        int srcl = n;
        float4 p4 = make_float4(0.f, 0.f, 0.f, 0.f);
        if (idx < cnt) {
            srcl = (idx == 0) ? n : col[beg + idx - 1];
            float4 a4 = *(const float4*)(as_ + (size_t)srcl * 4);
            float e;
            e = a4.x + ad4.x; e = e > 0.f ? e : 0.2f * e; p4.x = __expf(e);
            e = a4.y + ad4.y; e = e > 0.f ? e : 0.2f * e; p4.y = __expf(e);
            e = a4.z + ad4.z; e = e > 0.f ? e : 0.2f * e; p4.z = __expf(e);
            e = a4.w + ad4.w; e = e > 0.f ? e : 0.2f * e; p4.w = __expf(e);
        }
        sp.x += p4.x; sp.y += p4.y; sp.z += p4.z; sp.w += p4.w;
        s_src[wv][lane] = srcl;
        s_p[wv][lane] = p4;
        int jmax = min(64, cnt - c);
        #pragma unroll 4
        for (int j = 0; j < jmax; ++j) {
            int srcj = s_src[wv][j];                          // uniform -> broadcast
            float pj = ((const float*)&s_p[wv][j])[head];     // 4 banks, 16-lane broadcast each
            ushort4 hv = *(const ushort4*)(Hb + (size_t)srcj * HC1 + lane * 4);
            ax = fmaf(pj, bf2f(hv.x), ax);
            ay = fmaf(pj, bf2f(hv.y), ay);
            az = fmaf(pj, bf2f(hv.z), az);
            aw = fmaf(pj, bf2f(hv.w), aw);
        }
    }
    #pragma unroll
    for (int off = 1; off < 64; off <<= 1) {
        sp.x += __shfl_xor(sp.x, off);
        sp.y += __shfl_xor(sp.y, off);
        sp.z += __shfl_xor(sp.z, off);
        sp.w += __shfl_xor(sp.w, off);
    }
    float s = head < 2 ? (head == 0 ? sp.x : sp.y) : (head == 2 ? sp.z : sp.w);
    float inv = 1.f / s;
    float4 bv = *(const float4*)(bias + lane * 4);
    float4 o;
    o.x = ax * inv + bv.x;
    o.y = ay * inv + bv.y;
    o.z = az * inv + bv.z;
    o.w = aw * inv + bv.w;
    o.x = o.x > 0.f ? o.x : __expf(o.x) - 1.f;   // ELU
    o.y = o.y > 0.f ? o.y : __expf(o.y) - 1.f;
    o.z = o.z > 0.f ? o.z : __expf(o.z) - 1.f;
    o.w = o.w > 0.f ? o.w : __expf(o.w) - 1.f;
    ushort4 ob;
    ob.x = f2bf(o.x); ob.y = f2bf(o.y); ob.z = f2bf(o.z); ob.w = f2bf(o.w);
    *(ushort4*)(outp + (size_t)n * HC1 + lane * 4) = ob;
}

// ---------------- aggregation layer 2: wave/dst, LDS (src,p) staging, bf16 gather ----------------
__global__ __launch_bounds__(256) void k_agg2(
    const int* __restrict__ row_ptr, const int* __restrict__ col,
    const u16* __restrict__ Hb, const float* __restrict__ as_, const float* __restrict__ ad_,
    const float* __restrict__ bias, float* __restrict__ outp)
{
    __shared__ int   s_src[4][64];
    __shared__ float s_p[4][64];
    int n = blockIdx.x * 4 + (threadIdx.x >> 6);
    if (n >= NN) return;
    const int lane = threadIdx.x & 63;
    const int wv = threadIdx.x >> 6;
    float ad0 = ad_[n];
    int beg = row_ptr[n];
    int cnt = row_ptr[n + 1] - beg + 1;
    float sp = 0.f;
    float ax = 0.f, ay = 0.f;
    for (int c = 0; c < cnt; c += 64) {
        int idx = c + lane;
        int srcl = n;
        float p = 0.f;
        if (idx < cnt) {
            srcl = (idx == 0) ? n : col[beg + idx - 1];
            float e = as_[srcl] + ad0;
            e = e > 0.f ? e : 0.2f * e;
            p = __expf(e);
        }
        sp += p;
        s_src[wv][lane] = srcl;
        s_p[wv][lane] = p;
        int jmax = min(64, cnt - c);
        #pragma unroll 4
        for (int j = 0; j < jmax; ++j) {
            int srcj = s_src[wv][j];
            float pj = s_p[wv][j];
            ushort2 hv = *(const ushort2*)(Hb + (size_t)srcj * HC2 + lane * 2);
            ax = fmaf(pj, bf2f(hv.x), ax);
            ay = fmaf(pj, bf2f(hv.y), ay);
        }
    }
    #pragma unroll
    for (int off = 1; off < 64; off <<= 1) sp += __shfl_xor(sp, off);
    float inv = 1.f / sp;
    float2 bv = *(const float2*)(bias + lane * 2);
    float2 o = make_float2(ax * inv + bv.x, ay * inv + bv.y);
    *(float2*)(outp + (size_t)n * HC2 + lane * 2) = o;
}

// ---------------- launch ----------------
extern "C" void kernel_launch(void* const* d_in, const int* in_sizes, int n_in,
                              void* d_out, int out_size, void* d_ws, size_t ws_size,
                              hipStream_t stream) {
    const float* x   = (const float*)d_in[0];
    const int*       e32 = (const int*)d_in[1];
    const long long* e64 = (const long long*)d_in[1];
    const float* W1  = (const float*)d_in[2];
    const float* as1w = (const float*)d_in[3];
    const float* ad1w = (const float*)d_in[4];
    const float* b1  = (const float*)d_in[5];
    const float* W2  = (const float*)d_in[6];
    const float* as2w = (const float*)d_in[7];
    const float* ad2w = (const float*)d_in[8];
    const float* b2  = (const float*)d_in[9];
    float* out = (float*)d_out;

    char* w = (char*)d_ws;
    auto carve = [&](size_t bytes) -> void* {
        void* p = (void*)w;
        w += (bytes + 255) & ~(size_t)255;
        return p;
    };
    int*   flag    = (int*)carve(4);
    int*   row_ptr = (int*)carve((NN + 1) * sizeof(int));
    int*   cursor  = (int*)carve(NN * sizeof(int));
    int*   col     = (int*)carve(NE * sizeof(int));
    int*   bsum    = (int*)carve(256 * sizeof(int));
    int*   boff    = (int*)carve(256 * sizeof(int));
    float* as1     = (float*)carve((size_t)NN * H1 * sizeof(float));
    float* ad1     = (float*)carve((size_t)NN * H1 * sizeof(float));
    float* as2     = (float*)carve((size_t)NN * sizeof(float));
    float* ad2     = (float*)carve((size_t)NN * sizeof(float));
    u16*   xb      = (u16*)carve((size_t)NN * F1 * sizeof(u16));      // bf16 x
    u16*   h1b     = (u16*)carve((size_t)NN * HC1 * sizeof(u16));     // bf16 layer-1 features
    u16*   h2in    = (u16*)carve((size_t)NN * HC1 * sizeof(u16));     // bf16 ELU output -> GEMM2 A
    u16*   h2b     = (u16*)carve((size_t)NN * HC2 * sizeof(u16));     // bf16 layer-2 features
    u16*   wp1     = (u16*)carve((size_t)F1 * HC1 * sizeof(u16));     // packed W1
    u16*   wp2     = (u16*)carve((size_t)HC1 * HC2 * sizeof(u16));    // packed W2

    const int TPB = 256;
    const int gN  = (NN + TPB - 1) / TPB;      // 196
    const int gE  = (NE + TPB - 1) / TPB;
    const int gM  = (NN + 63) / 64;            // 782
    const int gAgg = (NN + 3) / 4;

    // input prep
    k_cvt<<<(NN * F1 / 8 + 255) / 256, 256, 0, stream>>>(x, xb, NN * F1 / 8);
    k_prepw<F1, HC1><<<F1 * HC1 / 256, 256, 0, stream>>>(W1, wp1);
    k_prepw<HC1, HC2><<<HC1 * HC2 / 256, 256, 0, stream>>>(W2, wp2);

    // CSR build
    k_zero_detect<<<gN, TPB, 0, stream>>>(cursor, e32, flag);
    k_count<<<gE, TPB, 0, stream>>>(e32, e64, flag, cursor);
    k_part<<<gN, TPB, 0, stream>>>(cursor, bsum);
    k_scanb<<<1, 256, 0, stream>>>(bsum, boff, row_ptr, gN);
    k_addb<<<gN, TPB, 0, stream>>>(cursor, boff, row_ptr, cursor);
    k_fill<<<gE, TPB, 0, stream>>>(e32, e64, flag, cursor, col);

    // layer 1
    k_gemm_mfma<F1, HC1, H1, 256><<<gM, 256, 0, stream>>>(xb, wp1, as1w, ad1w, h1b, as1, ad1, NN);
    k_agg1<<<gAgg, TPB, 0, stream>>>(row_ptr, col, h1b, as1, ad1, b1, h2in);

    // layer 2
    k_gemm_mfma<HC1, HC2, 1, 128><<<gM, 128, 0, stream>>>(h2in, wp2, as2w, ad2w, h2b, as2, ad2, NN);
    k_agg2<<<gAgg, TPB, 0, stream>>>(row_ptr, col, h2b, as2, ad2, b2, out);
}

// Round 12
// 238.635 us; speedup vs baseline: 1.9315x; 1.0094x over previous
//
#include <hip/hip_runtime.h>

#define NN 50000
#define NE 800000

constexpr int H1 = 4, F1 = 128, HC1 = 256;
constexpr int HC2 = 128;
constexpr int GM1 = (NN + 63) / 64;     // 782 gemm blocks (layer 1)
constexpr int GE  = (NE + 255) / 256;   // 3125 edge blocks

typedef unsigned short u16;
typedef unsigned int u32;
typedef __attribute__((ext_vector_type(8))) short bf16x8;
typedef __attribute__((ext_vector_type(4))) float f32x4;

__device__ __forceinline__ float bf2f(u16 h) {
    return __uint_as_float(((u32)h) << 16);
}
__device__ __forceinline__ u16 f2bf(float f) {
    u32 u = __float_as_uint(f);
    u32 r = (u + 0x7fffu + ((u >> 16) & 1u)) >> 16;   // RTN-even
    return (u16)r;
}

__device__ __forceinline__ int ld_edge(const int* e32, const long long* e64, int is64, long long idx) {
    return is64 ? (int)e64[idx] : e32[idx];
}

// ---------------- fused prep: [0,3125) x->bf16 | [3125,3253) wp1 | [3253,3381) wp2 | [3381,3577) zero+detect ----
__global__ __launch_bounds__(256) void k_prep(
    const float* __restrict__ x, const float* __restrict__ W1, const float* __restrict__ W2,
    u16* __restrict__ xb, u16* __restrict__ wp1, u16* __restrict__ wp2,
    int* __restrict__ deg, const int* __restrict__ e32, int* __restrict__ flag)
{
    const int b = blockIdx.x, tid = threadIdx.x;
    if (b < 3125) {                       // cvt: 3125*256*8 == NN*F1
        int i = b * 256 + tid;
        const float4* p = (const float4*)x + (size_t)i * 2;
        float4 a = p[0], c = p[1];
        ushort4 o0, o1;
        o0.x = f2bf(a.x); o0.y = f2bf(a.y); o0.z = f2bf(a.z); o0.w = f2bf(a.w);
        o1.x = f2bf(c.x); o1.y = f2bf(c.y); o1.z = f2bf(c.z); o1.w = f2bf(c.w);
        ((ushort4*)xb)[(size_t)i * 2] = o0;
        ((ushort4*)xb)[(size_t)i * 2 + 1] = o1;
    } else if (b < 3253) {                // wp1: [NK][256][4][8] <- W1[128][256]
        int o = (b - 3125) * 256 + tid;
        int j = o & 7, lk = (o >> 3) & 3, nn = (o >> 5) & 255, kc = o >> 13;
        int k = kc * 32 + lk * 8 + j;
        wp1[o] = f2bf(W1[(size_t)k * HC1 + nn]);
    } else if (b < 3381) {                // wp2: [NK][128][4][8] <- W2[256][128]
        int o = (b - 3253) * 256 + tid;
        int j = o & 7, lk = (o >> 3) & 3, nn = (o >> 5) & 127, kc = o >> 12;
        int k = kc * 32 + lk * 8 + j;
        wp2[o] = f2bf(W2[(size_t)k * HC2 + nn]);
    } else {                              // zero deg + int64 detect
        int i = (b - 3381) * 256 + tid;
        if (i < NN) deg[i] = 0;
        if (b == 3381 && tid == 0) {
            int z = 1;
            for (int t = 0; t < 16; t++)
                if (e32[2 * t + 1] != 0) z = 0;
            *flag = z;
        }
    }
}

__global__ void k_count(const int* __restrict__ e32, const long long* __restrict__ e64,
                        const int* __restrict__ flag, int* __restrict__ deg) {
    int e = blockIdx.x * blockDim.x + threadIdx.x;
    if (e >= NE) return;
    int is64 = *flag;
    int dst = ld_edge(e32, e64, is64, (long long)NE + e);
    atomicAdd(&deg[dst], 1);
}

__global__ __launch_bounds__(256) void k_part(const int* __restrict__ deg, int* __restrict__ bsum) {
    int i = blockIdx.x * 256 + threadIdx.x;
    int v = (i < NN) ? deg[i] : 0;
    #pragma unroll
    for (int off = 1; off < 64; off <<= 1) v += __shfl_xor(v, off);
    __shared__ int ws[4];
    if ((threadIdx.x & 63) == 0) ws[threadIdx.x >> 6] = v;
    __syncthreads();
    if (threadIdx.x == 0) bsum[blockIdx.x] = ws[0] + ws[1] + ws[2] + ws[3];
}

__global__ __launch_bounds__(256) void k_scanb(const int* __restrict__ bsum, int* __restrict__ boff,
                                               int* __restrict__ row_ptr, int NB) {
    const int tid = threadIdx.x;
    const int lane = tid & 63, wv = tid >> 6;
    int v = (tid < NB) ? bsum[tid] : 0;
    int x = v;
    #pragma unroll
    for (int off = 1; off < 64; off <<= 1) {
        int t = __shfl_up(x, off);
        if (lane >= off) x += t;
    }
    __shared__ int wsum[4], woff[4];
    if (lane == 63) wsum[wv] = x;
    __syncthreads();
    if (tid == 0) {
        int run = 0;
        #pragma unroll
        for (int j = 0; j < 4; j++) { woff[j] = run; run += wsum[j]; }
        row_ptr[NN] = run;
    }
    __syncthreads();
    if (tid < NB) boff[tid] = x - v + woff[wv];
}

__global__ __launch_bounds__(256) void k_addb(const int* __restrict__ deg, const int* __restrict__ boff,
                                              int* __restrict__ row_ptr, int* __restrict__ cursor) {
    const int tid = threadIdx.x;
    const int lane = tid & 63, wv = tid >> 6;
    int i = blockIdx.x * 256 + tid;
    int v = (i < NN) ? deg[i] : 0;
    int x = v;
    #pragma unroll
    for (int off = 1; off < 64; off <<= 1) {
        int t = __shfl_up(x, off);
        if (lane >= off) x += t;
    }
    __shared__ int wsum[4], woff[4];
    if (lane == 63) wsum[wv] = x;
    __syncthreads();
    if (tid == 0) {
        int run = 0;
        #pragma unroll
        for (int j = 0; j < 4; j++) { woff[j] = run; run += wsum[j]; }
    }
    __syncthreads();
    int excl = x - v + woff[wv] + boff[blockIdx.x];
    if (i < NN) { row_ptr[i] = excl; cursor[i] = excl; }
}

// ---------------- MFMA GEMM body (+ attention-logit epilogue), callable from fused kernels ------
template <int K, int NOUT, int HEADS, int TPB>
__device__ __forceinline__ void gemm_body(
    int bid, const u16* __restrict__ Ab, const u16* __restrict__ Wp,
    const float* __restrict__ atts, const float* __restrict__ attd,
    u16* __restrict__ Hout, float* __restrict__ as_out, float* __restrict__ ad_out, int M)
{
    constexpr int BM = 64, BK = 32;
    constexpr int NK = K / BK;
    constexpr int C = NOUT / HEADS;
    constexpr int LDA = 40;                         // u16 per LDS row (80 B padded)
    __shared__ __align__(16) u16 As[2][BM * LDA];
    __shared__ float red_s[BM * HEADS];
    __shared__ float red_d[BM * HEADS];

    const int tid = threadIdx.x;
    const int w = tid >> 6;
    const int l = tid & 63;
    const int l15 = l & 15, lk = l >> 4;
    const int row0 = bid * BM;
    const int col0 = w * 64;

    for (int i = tid; i < BM * HEADS; i += TPB) { red_s[i] = 0.f; red_d[i] = 0.f; }

    f32x4 acc[4][4];
    #pragma unroll
    for (int rt = 0; rt < 4; rt++)
        #pragma unroll
        for (int nt = 0; nt < 4; nt++)
            acc[rt][nt] = (f32x4){0.f, 0.f, 0.f, 0.f};

    auto stage = [&](int kc, int b) {
        #pragma unroll
        for (int i = tid; i < BM * 4; i += TPB) {
            int r = i >> 2, c = (i & 3) * 8;
            int gr = row0 + r;
            bf16x8 v = {0, 0, 0, 0, 0, 0, 0, 0};
            if (gr < M) v = *(const bf16x8*)(Ab + (size_t)gr * K + kc * BK + c);
            *(bf16x8*)&As[b][r * LDA + c] = v;
        }
    };
    auto loadB = [&](int kc, bf16x8* bf) {
        #pragma unroll
        for (int nt = 0; nt < 4; nt++)
            bf[nt] = *(const bf16x8*)(Wp + (((size_t)kc * NOUT + col0 + nt * 16 + l15) * 4 + lk) * 8);
    };

    bf16x8 bcur[4];
    loadB(0, bcur);
    stage(0, 0);
    for (int kc = 0; kc < NK; ++kc) {
        __syncthreads();
        bf16x8 afr[4];
        #pragma unroll
        for (int rt = 0; rt < 4; rt++)
            afr[rt] = *(const bf16x8*)&As[kc & 1][(rt * 16 + l15) * LDA + lk * 8];
        bf16x8 bnext[4];
        if (kc + 1 < NK) {
            loadB(kc + 1, bnext);
            stage(kc + 1, (kc + 1) & 1);
        }
        #pragma unroll
        for (int rt = 0; rt < 4; rt++)
            #pragma unroll
            for (int nt = 0; nt < 4; nt++)
                acc[rt][nt] = __builtin_amdgcn_mfma_f32_16x16x32_bf16(afr[rt], bcur[nt], acc[rt][nt], 0, 0, 0);
        if (kc + 1 < NK) {
            #pragma unroll
            for (int nt = 0; nt < 4; nt++) bcur[nt] = bnext[nt];
        }
    }

    // D layout col=l&15, row=(l>>4)*4+t  [m89-verified]
    #pragma unroll
    for (int rt = 0; rt < 4; rt++) {
        #pragma unroll
        for (int t = 0; t < 4; t++) {
            int gr = row0 + rt * 16 + lk * 4 + t;
            if (gr < M) {
                #pragma unroll
                for (int nt = 0; nt < 4; nt++)
                    Hout[(size_t)gr * NOUT + col0 + nt * 16 + l15] = f2bf(acc[rt][nt][t]);
            }
        }
    }

    float avs[4], avd[4];
    #pragma unroll
    for (int nt = 0; nt < 4; nt++) {
        int gc = col0 + nt * 16 + l15;
        avs[nt] = atts[gc];
        avd[nt] = attd[gc];
    }
    const int headw = col0 / C;
    #pragma unroll
    for (int rt = 0; rt < 4; rt++) {
        #pragma unroll
        for (int t = 0; t < 4; t++) {
            float ps = 0.f, pd = 0.f;
            #pragma unroll
            for (int nt = 0; nt < 4; nt++) {
                ps = fmaf(acc[rt][nt][t], avs[nt], ps);
                pd = fmaf(acc[rt][nt][t], avd[nt], pd);
            }
            ps += __shfl_xor(ps, 1); ps += __shfl_xor(ps, 2);
            ps += __shfl_xor(ps, 4); ps += __shfl_xor(ps, 8);
            pd += __shfl_xor(pd, 1); pd += __shfl_xor(pd, 2);
            pd += __shfl_xor(pd, 4); pd += __shfl_xor(pd, 8);
            if (l15 == 0) {
                int row = rt * 16 + lk * 4 + t;
                atomicAdd(&red_s[row * HEADS + headw], ps);
                atomicAdd(&red_d[row * HEADS + headw], pd);
            }
        }
    }
    __syncthreads();
    for (int i = tid; i < BM * HEADS; i += TPB) {
        int gr = row0 + i / HEADS;
        if (gr < M) {
            as_out[(size_t)gr * HEADS + i % HEADS] = red_s[i];
            ad_out[(size_t)gr * HEADS + i % HEADS] = red_d[i];
        }
    }
}

// ---------------- fused: gemm1 (+logits) | CSR fill (independent chains overlap) ----------------
__global__ __launch_bounds__(256) void k_gemm1_fill(
    const u16* __restrict__ xb, const u16* __restrict__ wp1,
    const float* __restrict__ as1w, const float* __restrict__ ad1w,
    u16* __restrict__ h1b, float* __restrict__ as1, float* __restrict__ ad1,
    const int* __restrict__ e32, const long long* __restrict__ e64,
    const int* __restrict__ flag, int* __restrict__ cursor, int* __restrict__ col)
{
    if (blockIdx.x < GM1) {
        gemm_body<F1, HC1, H1, 256>(blockIdx.x, xb, wp1, as1w, ad1w, h1b, as1, ad1, NN);
    } else {
        int e = (blockIdx.x - GM1) * 256 + threadIdx.x;
        if (e >= NE) return;
        int is64 = *flag;
        int src = ld_edge(e32, e64, is64, e);
        int dst = ld_edge(e32, e64, is64, (long long)NE + e);
        int pos = atomicAdd(&cursor[dst], 1);
        col[pos] = src;
    }
}

// ---------------- gemm2 standalone ----------------
template <int K, int NOUT, int HEADS, int TPB>
__global__ __launch_bounds__(TPB) void k_gemm_mfma(
    const u16* __restrict__ Ab, const u16* __restrict__ Wp,
    const float* __restrict__ atts, const float* __restrict__ attd,
    u16* __restrict__ Hout, float* __restrict__ as_out, float* __restrict__ ad_out, int M)
{
    gemm_body<K, NOUT, HEADS, TPB>(blockIdx.x, Ab, Wp, atts, attd, Hout, as_out, ad_out, M);
}

// ---------------- aggregation layer 1: 2 edges/iter (2x32 lanes), 16B/lane bf16x8 gather --------
__global__ __launch_bounds__(256) void k_agg1(
    const int* __restrict__ row_ptr, const int* __restrict__ col,
    const u16* __restrict__ Hb, const float* __restrict__ as_, const float* __restrict__ ad_,
    const float* __restrict__ bias, u16* __restrict__ outp)
{
    __shared__ int    s_src[4][64];
    __shared__ float4 s_p[4][64];
    int n = blockIdx.x * 4 + (threadIdx.x >> 6);
    const int lane = threadIdx.x & 63;
    const int wv = threadIdx.x >> 6;
    const int half = lane >> 5, l32 = lane & 31;
    const int head8 = l32 >> 3;                 // head of channels l32*8 .. l32*8+7
    float4 ad4 = *(const float4*)(ad_ + (size_t)n * 4);
    int beg = row_ptr[n];
    int cnt = row_ptr[n + 1] - beg + 1;         // +1: self loop first
    float4 sp = make_float4(0.f, 0.f, 0.f, 0.f);
    float a0 = 0.f, a1 = 0.f, a2 = 0.f, a3 = 0.f;
    float a4 = 0.f, a5 = 0.f, a6 = 0.f, a7 = 0.f;
    for (int c = 0; c < cnt; c += 64) {
        int idx = c + lane;
        int srcl = n;
        float4 p4 = make_float4(0.f, 0.f, 0.f, 0.f);
        if (idx < cnt) {
            srcl = (idx == 0) ? n : col[beg + idx - 1];
            float4 aa = *(const float4*)(as_ + (size_t)srcl * 4);
            float e;
            e = aa.x + ad4.x; e = e > 0.f ? e : 0.2f * e; p4.x = __expf(e);
            e = aa.y + ad4.y; e = e > 0.f ? e : 0.2f * e; p4.y = __expf(e);
            e = aa.z + ad4.z; e = e > 0.f ? e : 0.2f * e; p4.z = __expf(e);
            e = aa.w + ad4.w; e = e > 0.f ? e : 0.2f * e; p4.w = __expf(e);
        }
        sp.x += p4.x; sp.y += p4.y; sp.z += p4.z; sp.w += p4.w;
        s_src[wv][lane] = srcl;
        s_p[wv][lane] = p4;
        int jmax = min(64, cnt - c);
        #pragma unroll 4
        for (int j = 0; j < jmax; j += 2) {
            int jj = j + half;                                // padded entries have p=0
            int srcj = s_src[wv][jj];
            float pj = ((const float*)&s_p[wv][jj])[head8];
            bf16x8 hv = *(const bf16x8*)(Hb + (size_t)srcj * HC1 + l32 * 8);
            a0 = fmaf(pj, bf2f((u16)hv[0]), a0);
            a1 = fmaf(pj, bf2f((u16)hv[1]), a1);
            a2 = fmaf(pj, bf2f((u16)hv[2]), a2);
            a3 = fmaf(pj, bf2f((u16)hv[3]), a3);
            a4 = fmaf(pj, bf2f((u16)hv[4]), a4);
            a5 = fmaf(pj, bf2f((u16)hv[5]), a5);
            a6 = fmaf(pj, bf2f((u16)hv[6]), a6);
            a7 = fmaf(pj, bf2f((u16)hv[7]), a7);
        }
    }
    // combine the two edge-halves
    a0 += __shfl_xor(a0, 32); a1 += __shfl_xor(a1, 32);
    a2 += __shfl_xor(a2, 32); a3 += __shfl_xor(a3, 32);
    a4 += __shfl_xor(a4, 32); a5 += __shfl_xor(a5, 32);
    a6 += __shfl_xor(a6, 32); a7 += __shfl_xor(a7, 32);
    #pragma unroll
    for (int off = 1; off < 64; off <<= 1) {
        sp.x += __shfl_xor(sp.x, off);
        sp.y += __shfl_xor(sp.y, off);
        sp.z += __shfl_xor(sp.z, off);
        sp.w += __shfl_xor(sp.w, off);
    }
    if (lane < 32) {
        float s = head8 < 2 ? (head8 == 0 ? sp.x : sp.y) : (head8 == 2 ? sp.z : sp.w);
        float inv = 1.f / s;
        int ch0 = l32 * 8;
        float4 bv0 = *(const float4*)(bias + ch0);
        float4 bv1 = *(const float4*)(bias + ch0 + 4);
        float o0 = a0 * inv + bv0.x, o1 = a1 * inv + bv0.y;
        float o2 = a2 * inv + bv0.z, o3 = a3 * inv + bv0.w;
        float o4 = a4 * inv + bv1.x, o5 = a5 * inv + bv1.y;
        float o6 = a6 * inv + bv1.z, o7 = a7 * inv + bv1.w;
        o0 = o0 > 0.f ? o0 : __expf(o0) - 1.f;   // ELU
        o1 = o1 > 0.f ? o1 : __expf(o1) - 1.f;
        o2 = o2 > 0.f ? o2 : __expf(o2) - 1.f;
        o3 = o3 > 0.f ? o3 : __expf(o3) - 1.f;
        o4 = o4 > 0.f ? o4 : __expf(o4) - 1.f;
        o5 = o5 > 0.f ? o5 : __expf(o5) - 1.f;
        o6 = o6 > 0.f ? o6 : __expf(o6) - 1.f;
        o7 = o7 > 0.f ? o7 : __expf(o7) - 1.f;
        bf16x8 ob;
        ob[0] = (short)f2bf(o0); ob[1] = (short)f2bf(o1);
        ob[2] = (short)f2bf(o2); ob[3] = (short)f2bf(o3);
        ob[4] = (short)f2bf(o4); ob[5] = (short)f2bf(o5);
        ob[6] = (short)f2bf(o6); ob[7] = (short)f2bf(o7);
        *(bf16x8*)(outp + (size_t)n * HC1 + ch0) = ob;
    }
}

// ---------------- aggregation layer 2: 2 edges/iter (2x32 lanes), 8B/lane ushort4 gather --------
__global__ __launch_bounds__(256) void k_agg2(
    const int* __restrict__ row_ptr, const int* __restrict__ col,
    const u16* __restrict__ Hb, const float* __restrict__ as_, const float* __restrict__ ad_,
    const float* __restrict__ bias, float* __restrict__ outp)
{
    __shared__ int   s_src[4][64];
    __shared__ float s_p[4][64];
    int n = blockIdx.x * 4 + (threadIdx.x >> 6);
    const int lane = threadIdx.x & 63;
    const int wv = threadIdx.x >> 6;
    const int half = lane >> 5, l32 = lane & 31;
    float ad0 = ad_[n];
    int beg = row_ptr[n];
    int cnt = row_ptr[n + 1] - beg + 1;
    float sp = 0.f;
    float a0 = 0.f, a1 = 0.f, a2 = 0.f, a3 = 0.f;
    for (int c = 0; c < cnt; c += 64) {
        int idx = c + lane;
        int srcl = n;
        float p = 0.f;
        if (idx < cnt) {
            srcl = (idx == 0) ? n : col[beg + idx - 1];
            float e = as_[srcl] + ad0;
            e = e > 0.f ? e : 0.2f * e;
            p = __expf(e);
        }
        sp += p;
        s_src[wv][lane] = srcl;
        s_p[wv][lane] = p;
        int jmax = min(64, cnt - c);
        #pragma unroll 4
        for (int j = 0; j < jmax; j += 2) {
            int jj = j + half;
            int srcj = s_src[wv][jj];
            float pj = s_p[wv][jj];
            ushort4 hv = *(const ushort4*)(Hb + (size_t)srcj * HC2 + l32 * 4);
            a0 = fmaf(pj, bf2f(hv.x), a0);
            a1 = fmaf(pj, bf2f(hv.y), a1);
            a2 = fmaf(pj, bf2f(hv.z), a2);
            a3 = fmaf(pj, bf2f(hv.w), a3);
        }
    }
    a0 += __shfl_xor(a0, 32); a1 += __shfl_xor(a1, 32);
    a2 += __shfl_xor(a2, 32); a3 += __shfl_xor(a3, 32);
    #pragma unroll
    for (int off = 1; off < 64; off <<= 1) sp += __shfl_xor(sp, off);
    if (lane < 32) {
        float inv = 1.f / sp;
        int ch0 = l32 * 4;
        float4 bv = *(const float4*)(bias + ch0);
        float4 o;
        o.x = a0 * inv + bv.x;
        o.y = a1 * inv + bv.y;
        o.z = a2 * inv + bv.z;
        o.w = a3 * inv + bv.w;
        *(float4*)(outp + (size_t)n * HC2 + ch0) = o;
    }
}

// ---------------- launch ----------------
extern "C" void kernel_launch(void* const* d_in, const int* in_sizes, int n_in,
                              void* d_out, int out_size, void* d_ws, size_t ws_size,
                              hipStream_t stream) {
    const float* x   = (const float*)d_in[0];
    const int*       e32 = (const int*)d_in[1];
    const long long* e64 = (const long long*)d_in[1];
    const float* W1  = (const float*)d_in[2];
    const float* as1w = (const float*)d_in[3];
    const float* ad1w = (const float*)d_in[4];
    const float* b1  = (const float*)d_in[5];
    const float* W2  = (const float*)d_in[6];
    const float* as2w = (const float*)d_in[7];
    const float* ad2w = (const float*)d_in[8];
    const float* b2  = (const float*)d_in[9];
    float* out = (float*)d_out;

    char* w = (char*)d_ws;
    auto carve = [&](size_t bytes) -> void* {
        void* p = (void*)w;
        w += (bytes + 255) & ~(size_t)255;
        return p;
    };
    int*   flag    = (int*)carve(4);
    int*   row_ptr = (int*)carve((NN + 1) * sizeof(int));
    int*   cursor  = (int*)carve(NN * sizeof(int));
    int*   col     = (int*)carve(NE * sizeof(int));
    int*   bsum    = (int*)carve(256 * sizeof(int));
    int*   boff    = (int*)carve(256 * sizeof(int));
    float* as1     = (float*)carve((size_t)NN * H1 * sizeof(float));
    float* ad1     = (float*)carve((size_t)NN * H1 * sizeof(float));
    float* as2     = (float*)carve((size_t)NN * sizeof(float));
    float* ad2     = (float*)carve((size_t)NN * sizeof(float));
    u16*   xb      = (u16*)carve((size_t)NN * F1 * sizeof(u16));
    u16*   h1b     = (u16*)carve((size_t)NN * HC1 * sizeof(u16));
    u16*   h2in    = (u16*)carve((size_t)NN * HC1 * sizeof(u16));
    u16*   h2b     = (u16*)carve((size_t)NN * HC2 * sizeof(u16));
    u16*   wp1     = (u16*)carve((size_t)F1 * HC1 * sizeof(u16));
    u16*   wp2     = (u16*)carve((size_t)HC1 * HC2 * sizeof(u16));

    const int TPB = 256;
    const int gN  = (NN + TPB - 1) / TPB;      // 196
    const int gAgg = NN / 4;                   // 12500

    // prep (cvt | wp1 | wp2 | zero+detect)
    k_prep<<<3125 + 128 + 128 + 196, 256, 0, stream>>>(x, W1, W2, xb, wp1, wp2, cursor, e32, flag);

    // CSR build
    k_count<<<GE, TPB, 0, stream>>>(e32, e64, flag, cursor);
    k_part<<<gN, TPB, 0, stream>>>(cursor, bsum);
    k_scanb<<<1, 256, 0, stream>>>(bsum, boff, row_ptr, gN);
    k_addb<<<gN, TPB, 0, stream>>>(cursor, boff, row_ptr, cursor);

    // gemm1 (+logits) overlapped with CSR fill
    k_gemm1_fill<<<GM1 + GE, 256, 0, stream>>>(xb, wp1, as1w, ad1w, h1b, as1, ad1,
                                               e32, e64, flag, cursor, col);

    // layer 1 aggregation
    k_agg1<<<gAgg, TPB, 0, stream>>>(row_ptr, col, h1b, as1, ad1, b1, h2in);

    // layer 2
    k_gemm_mfma<HC1, HC2, 1, 128><<<GM1, 128, 0, stream>>>(h2in, wp2, as2w, ad2w, h2b, as2, ad2, NN);
    k_agg2<<<gAgg, TPB, 0, stream>>>(row_ptr, col, h2b, as2, ad2, b2, out);
}

// Round 13
// 237.325 us; speedup vs baseline: 1.9422x; 1.0055x over previous
//
#include <hip/hip_runtime.h>

#define NN 50000
#define NE 800000

constexpr int H1 = 4, F1 = 128, HC1 = 256;
constexpr int HC2 = 128;
constexpr int GM1 = (NN + 63) / 64;     // 782 gemm blocks
constexpr int GE  = (NE + 255) / 256;   // 3125 edge blocks

typedef unsigned short u16;
typedef unsigned int u32;
typedef __attribute__((ext_vector_type(8))) short bf16x8;
typedef __attribute__((ext_vector_type(4))) float f32x4;

__device__ __forceinline__ float bf2f(u16 h) {
    return __uint_as_float(((u32)h) << 16);
}
__device__ __forceinline__ u16 f2bf(float f) {
    u32 u = __float_as_uint(f);
    u32 r = (u + 0x7fffu + ((u >> 16) & 1u)) >> 16;   // RTN-even
    return (u16)r;
}

__device__ __forceinline__ int ld_edge(const int* e32, const long long* e64, int is64, long long idx) {
    return is64 ? (int)e64[idx] : e32[idx];
}

// ---------------- fused prep: [0,3125) x->bf16 | [3125,3253) wp1 | [3253,3381) wp2 | [3381,3577) zero+detect ----
__global__ __launch_bounds__(256) void k_prep(
    const float* __restrict__ x, const float* __restrict__ W1, const float* __restrict__ W2,
    u16* __restrict__ xb, u16* __restrict__ wp1, u16* __restrict__ wp2,
    int* __restrict__ deg, const int* __restrict__ e32, int* __restrict__ flag)
{
    const int b = blockIdx.x, tid = threadIdx.x;
    if (b < 3125) {                       // cvt: 3125*256*8 == NN*F1
        int i = b * 256 + tid;
        const float4* p = (const float4*)x + (size_t)i * 2;
        float4 a = p[0], c = p[1];
        ushort4 o0, o1;
        o0.x = f2bf(a.x); o0.y = f2bf(a.y); o0.z = f2bf(a.z); o0.w = f2bf(a.w);
        o1.x = f2bf(c.x); o1.y = f2bf(c.y); o1.z = f2bf(c.z); o1.w = f2bf(c.w);
        ((ushort4*)xb)[(size_t)i * 2] = o0;
        ((ushort4*)xb)[(size_t)i * 2 + 1] = o1;
    } else if (b < 3253) {                // wp1: [NK][256][4][8] <- W1[128][256]
        int o = (b - 3125) * 256 + tid;
        int j = o & 7, lk = (o >> 3) & 3, nn = (o >> 5) & 255, kc = o >> 13;
        int k = kc * 32 + lk * 8 + j;
        wp1[o] = f2bf(W1[(size_t)k * HC1 + nn]);
    } else if (b < 3381) {                // wp2: [NK][128][4][8] <- W2[256][128]
        int o = (b - 3253) * 256 + tid;
        int j = o & 7, lk = (o >> 3) & 3, nn = (o >> 5) & 127, kc = o >> 12;
        int k = kc * 32 + lk * 8 + j;
        wp2[o] = f2bf(W2[(size_t)k * HC2 + nn]);
    } else {                              // zero deg + int64 detect
        int i = (b - 3381) * 256 + tid;
        if (i < NN) deg[i] = 0;
        if (b == 3381 && tid == 0) {
            int z = 1;
            for (int t = 0; t < 16; t++)
                if (e32[2 * t + 1] != 0) z = 0;
            *flag = z;
        }
    }
}

__global__ void k_count(const int* __restrict__ e32, const long long* __restrict__ e64,
                        const int* __restrict__ flag, int* __restrict__ deg) {
    int e = blockIdx.x * blockDim.x + threadIdx.x;
    if (e >= NE) return;
    int is64 = *flag;
    int dst = ld_edge(e32, e64, is64, (long long)NE + e);
    atomicAdd(&deg[dst], 1);
}

__global__ __launch_bounds__(256) void k_part(const int* __restrict__ deg, int* __restrict__ bsum) {
    int i = blockIdx.x * 256 + threadIdx.x;
    int v = (i < NN) ? deg[i] : 0;
    #pragma unroll
    for (int off = 1; off < 64; off <<= 1) v += __shfl_xor(v, off);
    __shared__ int ws[4];
    if ((threadIdx.x & 63) == 0) ws[threadIdx.x >> 6] = v;
    __syncthreads();
    if (threadIdx.x == 0) bsum[blockIdx.x] = ws[0] + ws[1] + ws[2] + ws[3];
}

__global__ __launch_bounds__(256) void k_scanb(const int* __restrict__ bsum, int* __restrict__ boff,
                                               int* __restrict__ row_ptr, int NB) {
    const int tid = threadIdx.x;
    const int lane = tid & 63, wv = tid >> 6;
    int v = (tid < NB) ? bsum[tid] : 0;
    int x = v;
    #pragma unroll
    for (int off = 1; off < 64; off <<= 1) {
        int t = __shfl_up(x, off);
        if (lane >= off) x += t;
    }
    __shared__ int wsum[4], woff[4];
    if (lane == 63) wsum[wv] = x;
    __syncthreads();
    if (tid == 0) {
        int run = 0;
        #pragma unroll
        for (int j = 0; j < 4; j++) { woff[j] = run; run += wsum[j]; }
        row_ptr[NN] = run;
    }
    __syncthreads();
    if (tid < NB) boff[tid] = x - v + woff[wv];
}

__global__ __launch_bounds__(256) void k_addb(const int* __restrict__ deg, const int* __restrict__ boff,
                                              int* __restrict__ row_ptr, int* __restrict__ cursor) {
    const int tid = threadIdx.x;
    const int lane = tid & 63, wv = tid >> 6;
    int i = blockIdx.x * 256 + tid;
    int v = (i < NN) ? deg[i] : 0;
    int x = v;
    #pragma unroll
    for (int off = 1; off < 64; off <<= 1) {
        int t = __shfl_up(x, off);
        if (lane >= off) x += t;
    }
    __shared__ int wsum[4], woff[4];
    if (lane == 63) wsum[wv] = x;
    __syncthreads();
    if (tid == 0) {
        int run = 0;
        #pragma unroll
        for (int j = 0; j < 4; j++) { woff[j] = run; run += wsum[j]; }
    }
    __syncthreads();
    int excl = x - v + woff[wv] + boff[blockIdx.x];
    if (i < NN) { row_ptr[i] = excl; cursor[i] = excl; }
}

__global__ void k_fill(const int* __restrict__ e32, const long long* __restrict__ e64,
                       const int* __restrict__ flag, int* __restrict__ cursor, int* __restrict__ col) {
    int e = blockIdx.x * blockDim.x + threadIdx.x;
    if (e >= NE) return;
    int is64 = *flag;
    int src = ld_edge(e32, e64, is64, e);
    int dst = ld_edge(e32, e64, is64, (long long)NE + e);
    int pos = atomicAdd(&cursor[dst], 1);
    col[pos] = src;
}

// ---------------- MFMA GEMM body (+ attention-logit epilogue) ----------------
template <int K, int NOUT, int HEADS, int TPB>
__device__ __forceinline__ void gemm_body(
    int bid, const u16* __restrict__ Ab, const u16* __restrict__ Wp,
    const float* __restrict__ atts, const float* __restrict__ attd,
    u16* __restrict__ Hout, float* __restrict__ as_out, float* __restrict__ ad_out, int M)
{
    constexpr int BM = 64, BK = 32;
    constexpr int NK = K / BK;
    constexpr int C = NOUT / HEADS;
    constexpr int LDA = 40;                         // u16 per LDS row (80 B padded)
    __shared__ __align__(16) u16 As[2][BM * LDA];
    __shared__ float red_s[BM * HEADS];
    __shared__ float red_d[BM * HEADS];

    const int tid = threadIdx.x;
    const int w = tid >> 6;
    const int l = tid & 63;
    const int l15 = l & 15, lk = l >> 4;
    const int row0 = bid * BM;
    const int col0 = w * 64;

    for (int i = tid; i < BM * HEADS; i += TPB) { red_s[i] = 0.f; red_d[i] = 0.f; }

    f32x4 acc[4][4];
    #pragma unroll
    for (int rt = 0; rt < 4; rt++)
        #pragma unroll
        for (int nt = 0; nt < 4; nt++)
            acc[rt][nt] = (f32x4){0.f, 0.f, 0.f, 0.f};

    auto stage = [&](int kc, int b) {
        #pragma unroll
        for (int i = tid; i < BM * 4; i += TPB) {
            int r = i >> 2, c = (i & 3) * 8;
            int gr = row0 + r;
            bf16x8 v = {0, 0, 0, 0, 0, 0, 0, 0};
            if (gr < M) v = *(const bf16x8*)(Ab + (size_t)gr * K + kc * BK + c);
            *(bf16x8*)&As[b][r * LDA + c] = v;
        }
    };
    auto loadB = [&](int kc, bf16x8* bf) {
        #pragma unroll
        for (int nt = 0; nt < 4; nt++)
            bf[nt] = *(const bf16x8*)(Wp + (((size_t)kc * NOUT + col0 + nt * 16 + l15) * 4 + lk) * 8);
    };

    bf16x8 bcur[4];
    loadB(0, bcur);
    stage(0, 0);
    for (int kc = 0; kc < NK; ++kc) {
        __syncthreads();
        bf16x8 afr[4];
        #pragma unroll
        for (int rt = 0; rt < 4; rt++)
            afr[rt] = *(const bf16x8*)&As[kc & 1][(rt * 16 + l15) * LDA + lk * 8];
        bf16x8 bnext[4];
        if (kc + 1 < NK) {
            loadB(kc + 1, bnext);
            stage(kc + 1, (kc + 1) & 1);
        }
        #pragma unroll
        for (int rt = 0; rt < 4; rt++)
            #pragma unroll
            for (int nt = 0; nt < 4; nt++)
                acc[rt][nt] = __builtin_amdgcn_mfma_f32_16x16x32_bf16(afr[rt], bcur[nt], acc[rt][nt], 0, 0, 0);
        if (kc + 1 < NK) {
            #pragma unroll
            for (int nt = 0; nt < 4; nt++) bcur[nt] = bnext[nt];
        }
    }

    // D layout col=l&15, row=(l>>4)*4+t  [m89-verified]
    #pragma unroll
    for (int rt = 0; rt < 4; rt++) {
        #pragma unroll
        for (int t = 0; t < 4; t++) {
            int gr = row0 + rt * 16 + lk * 4 + t;
            if (gr < M) {
                #pragma unroll
                for (int nt = 0; nt < 4; nt++)
                    Hout[(size_t)gr * NOUT + col0 + nt * 16 + l15] = f2bf(acc[rt][nt][t]);
            }
        }
    }

    float avs[4], avd[4];
    #pragma unroll
    for (int nt = 0; nt < 4; nt++) {
        int gc = col0 + nt * 16 + l15;
        avs[nt] = atts[gc];
        avd[nt] = attd[gc];
    }
    const int headw = col0 / C;
    #pragma unroll
    for (int rt = 0; rt < 4; rt++) {
        #pragma unroll
        for (int t = 0; t < 4; t++) {
            float ps = 0.f, pd = 0.f;
            #pragma unroll
            for (int nt = 0; nt < 4; nt++) {
                ps = fmaf(acc[rt][nt][t], avs[nt], ps);
                pd = fmaf(acc[rt][nt][t], avd[nt], pd);
            }
            ps += __shfl_xor(ps, 1); ps += __shfl_xor(ps, 2);
            ps += __shfl_xor(ps, 4); ps += __shfl_xor(ps, 8);
            pd += __shfl_xor(pd, 1); pd += __shfl_xor(pd, 2);
            pd += __shfl_xor(pd, 4); pd += __shfl_xor(pd, 8);
            if (l15 == 0) {
                int row = rt * 16 + lk * 4 + t;
                atomicAdd(&red_s[row * HEADS + headw], ps);
                atomicAdd(&red_d[row * HEADS + headw], pd);
            }
        }
    }
    __syncthreads();
    for (int i = tid; i < BM * HEADS; i += TPB) {
        int gr = row0 + i / HEADS;
        if (gr < M) {
            as_out[(size_t)gr * HEADS + i % HEADS] = red_s[i];
            ad_out[(size_t)gr * HEADS + i % HEADS] = red_d[i];
        }
    }
}

template <int K, int NOUT, int HEADS, int TPB>
__global__ __launch_bounds__(TPB) void k_gemm_mfma(
    const u16* __restrict__ Ab, const u16* __restrict__ Wp,
    const float* __restrict__ atts, const float* __restrict__ attd,
    u16* __restrict__ Hout, float* __restrict__ as_out, float* __restrict__ ad_out, int M)
{
    gemm_body<K, NOUT, HEADS, TPB>(blockIdx.x, Ab, Wp, atts, attd, Hout, as_out, ad_out, M);
}

// ---------------- aggregation layer 1: 2 edges/iter (2x32 lanes), 16B/lane bf16x8 gather --------
__global__ __launch_bounds__(256) void k_agg1(
    const int* __restrict__ row_ptr, const int* __restrict__ col,
    const u16* __restrict__ Hb, const float* __restrict__ as_, const float* __restrict__ ad_,
    const float* __restrict__ bias, u16* __restrict__ outp)
{
    __shared__ int    s_src[4][64];
    __shared__ float4 s_p[4][64];
    int n = blockIdx.x * 4 + (threadIdx.x >> 6);
    const int lane = threadIdx.x & 63;
    const int wv = threadIdx.x >> 6;
    const int half = lane >> 5, l32 = lane & 31;
    const int head8 = l32 >> 3;                 // head of channels l32*8 .. l32*8+7
    float4 ad4 = *(const float4*)(ad_ + (size_t)n * 4);
    int beg = row_ptr[n];
    int cnt = row_ptr[n + 1] - beg + 1;         // +1: self loop first
    float4 sp = make_float4(0.f, 0.f, 0.f, 0.f);
    float a0 = 0.f, a1 = 0.f, a2 = 0.f, a3 = 0.f;
    float a4 = 0.f, a5 = 0.f, a6 = 0.f, a7 = 0.f;
    for (int c = 0; c < cnt; c += 64) {
        int idx = c + lane;
        int srcl = n;
        float4 p4 = make_float4(0.f, 0.f, 0.f, 0.f);
        if (idx < cnt) {
            srcl = (idx == 0) ? n : col[beg + idx - 1];
            float4 aa = *(const float4*)(as_ + (size_t)srcl * 4);
            float e;
            e = aa.x + ad4.x; e = e > 0.f ? e : 0.2f * e; p4.x = __expf(e);
            e = aa.y + ad4.y; e = e > 0.f ? e : 0.2f * e; p4.y = __expf(e);
            e = aa.z + ad4.z; e = e > 0.f ? e : 0.2f * e; p4.z = __expf(e);
            e = aa.w + ad4.w; e = e > 0.f ? e : 0.2f * e; p4.w = __expf(e);
        }
        sp.x += p4.x; sp.y += p4.y; sp.z += p4.z; sp.w += p4.w;
        s_src[wv][lane] = srcl;
        s_p[wv][lane] = p4;
        int jmax = min(64, cnt - c);
        #pragma unroll 4
        for (int j = 0; j < jmax; j += 2) {
            int jj = j + half;                                // padded entries have p=0
            int srcj = s_src[wv][jj];
            float pj = ((const float*)&s_p[wv][jj])[head8];
            bf16x8 hv = *(const bf16x8*)(Hb + (size_t)srcj * HC1 + l32 * 8);
            a0 = fmaf(pj, bf2f((u16)hv[0]), a0);
            a1 = fmaf(pj, bf2f((u16)hv[1]), a1);
            a2 = fmaf(pj, bf2f((u16)hv[2]), a2);
            a3 = fmaf(pj, bf2f((u16)hv[3]), a3);
            a4 = fmaf(pj, bf2f((u16)hv[4]), a4);
            a5 = fmaf(pj, bf2f((u16)hv[5]), a5);
            a6 = fmaf(pj, bf2f((u16)hv[6]), a6);
            a7 = fmaf(pj, bf2f((u16)hv[7]), a7);
        }
    }
    a0 += __shfl_xor(a0, 32); a1 += __shfl_xor(a1, 32);
    a2 += __shfl_xor(a2, 32); a3 += __shfl_xor(a3, 32);
    a4 += __shfl_xor(a4, 32); a5 += __shfl_xor(a5, 32);
    a6 += __shfl_xor(a6, 32); a7 += __shfl_xor(a7, 32);
    #pragma unroll
    for (int off = 1; off < 64; off <<= 1) {
        sp.x += __shfl_xor(sp.x, off);
        sp.y += __shfl_xor(sp.y, off);
        sp.z += __shfl_xor(sp.z, off);
        sp.w += __shfl_xor(sp.w, off);
    }
    if (lane < 32) {
        float s = head8 < 2 ? (head8 == 0 ? sp.x : sp.y) : (head8 == 2 ? sp.z : sp.w);
        float inv = 1.f / s;
        int ch0 = l32 * 8;
        float4 bv0 = *(const float4*)(bias + ch0);
        float4 bv1 = *(const float4*)(bias + ch0 + 4);
        float o0 = a0 * inv + bv0.x, o1 = a1 * inv + bv0.y;
        float o2 = a2 * inv + bv0.z, o3 = a3 * inv + bv0.w;
        float o4 = a4 * inv + bv1.x, o5 = a5 * inv + bv1.y;
        float o6 = a6 * inv + bv1.z, o7 = a7 * inv + bv1.w;
        o0 = o0 > 0.f ? o0 : __expf(o0) - 1.f;   // ELU
        o1 = o1 > 0.f ? o1 : __expf(o1) - 1.f;
        o2 = o2 > 0.f ? o2 : __expf(o2) - 1.f;
        o3 = o3 > 0.f ? o3 : __expf(o3) - 1.f;
        o4 = o4 > 0.f ? o4 : __expf(o4) - 1.f;
        o5 = o5 > 0.f ? o5 : __expf(o5) - 1.f;
        o6 = o6 > 0.f ? o6 : __expf(o6) - 1.f;
        o7 = o7 > 0.f ? o7 : __expf(o7) - 1.f;
        bf16x8 ob;
        ob[0] = (short)f2bf(o0); ob[1] = (short)f2bf(o1);
        ob[2] = (short)f2bf(o2); ob[3] = (short)f2bf(o3);
        ob[4] = (short)f2bf(o4); ob[5] = (short)f2bf(o5);
        ob[6] = (short)f2bf(o6); ob[7] = (short)f2bf(o7);
        *(bf16x8*)(outp + (size_t)n * HC1 + ch0) = ob;
    }
}

// ---------------- aggregation layer 2: 2 edges/iter (2x32 lanes), 8B/lane ushort4 gather --------
__global__ __launch_bounds__(256) void k_agg2(
    const int* __restrict__ row_ptr, const int* __restrict__ col,
    const u16* __restrict__ Hb, const float* __restrict__ as_, const float* __restrict__ ad_,
    const float* __restrict__ bias, float* __restrict__ outp)
{
    __shared__ int   s_src[4][64];
    __shared__ float s_p[4][64];
    int n = blockIdx.x * 4 + (threadIdx.x >> 6);
    const int lane = threadIdx.x & 63;
    const int wv = threadIdx.x >> 6;
    const int half = lane >> 5, l32 = lane & 31;
    float ad0 = ad_[n];
    int beg = row_ptr[n];
    int cnt = row_ptr[n + 1] - beg + 1;
    float sp = 0.f;
    float a0 = 0.f, a1 = 0.f, a2 = 0.f, a3 = 0.f;
    for (int c = 0; c < cnt; c += 64) {
        int idx = c + lane;
        int srcl = n;
        float p = 0.f;
        if (idx < cnt) {
            srcl = (idx == 0) ? n : col[beg + idx - 1];
            float e = as_[srcl] + ad0;
            e = e > 0.f ? e : 0.2f * e;
            p = __expf(e);
        }
        sp += p;
        s_src[wv][lane] = srcl;
        s_p[wv][lane] = p;
        int jmax = min(64, cnt - c);
        #pragma unroll 4
        for (int j = 0; j < jmax; j += 2) {
            int jj = j + half;
            int srcj = s_src[wv][jj];
            float pj = s_p[wv][jj];
            ushort4 hv = *(const ushort4*)(Hb + (size_t)srcj * HC2 + l32 * 4);
            a0 = fmaf(pj, bf2f(hv.x), a0);
            a1 = fmaf(pj, bf2f(hv.y), a1);
            a2 = fmaf(pj, bf2f(hv.z), a2);
            a3 = fmaf(pj, bf2f(hv.w), a3);
        }
    }
    a0 += __shfl_xor(a0, 32); a1 += __shfl_xor(a1, 32);
    a2 += __shfl_xor(a2, 32); a3 += __shfl_xor(a3, 32);
    #pragma unroll
    for (int off = 1; off < 64; off <<= 1) sp += __shfl_xor(sp, off);
    if (lane < 32) {
        float inv = 1.f / sp;
        int ch0 = l32 * 4;
        float4 bv = *(const float4*)(bias + ch0);
        float4 o;
        o.x = a0 * inv + bv.x;
        o.y = a1 * inv + bv.y;
        o.z = a2 * inv + bv.z;
        o.w = a3 * inv + bv.w;
        *(float4*)(outp + (size_t)n * HC2 + ch0) = o;
    }
}

// ---------------- launch ----------------
extern "C" void kernel_launch(void* const* d_in, const int* in_sizes, int n_in,
                              void* d_out, int out_size, void* d_ws, size_t ws_size,
                              hipStream_t stream) {
    const float* x   = (const float*)d_in[0];
    const int*       e32 = (const int*)d_in[1];
    const long long* e64 = (const long long*)d_in[1];
    const float* W1  = (const float*)d_in[2];
    const float* as1w = (const float*)d_in[3];
    const float* ad1w = (const float*)d_in[4];
    const float* b1  = (const float*)d_in[5];
    const float* W2  = (const float*)d_in[6];
    const float* as2w = (const float*)d_in[7];
    const float* ad2w = (const float*)d_in[8];
    const float* b2  = (const float*)d_in[9];
    float* out = (float*)d_out;

    char* w = (char*)d_ws;
    auto carve = [&](size_t bytes) -> void* {
        void* p = (void*)w;
        w += (bytes + 255) & ~(size_t)255;
        return p;
    };
    int*   flag    = (int*)carve(4);
    int*   row_ptr = (int*)carve((NN + 1) * sizeof(int));
    int*   cursor  = (int*)carve(NN * sizeof(int));
    int*   col     = (int*)carve(NE * sizeof(int));
    int*   bsum    = (int*)carve(256 * sizeof(int));
    int*   boff    = (int*)carve(256 * sizeof(int));
    float* as1     = (float*)carve((size_t)NN * H1 * sizeof(float));
    float* ad1     = (float*)carve((size_t)NN * H1 * sizeof(float));
    float* as2     = (float*)carve((size_t)NN * sizeof(float));
    float* ad2     = (float*)carve((size_t)NN * sizeof(float));
    u16*   xb      = (u16*)carve((size_t)NN * F1 * sizeof(u16));
    u16*   h1b     = (u16*)carve((size_t)NN * HC1 * sizeof(u16));
    u16*   h2in    = (u16*)carve((size_t)NN * HC1 * sizeof(u16));
    u16*   h2b     = (u16*)carve((size_t)NN * HC2 * sizeof(u16));
    u16*   wp1     = (u16*)carve((size_t)F1 * HC1 * sizeof(u16));
    u16*   wp2     = (u16*)carve((size_t)HC1 * HC2 * sizeof(u16));

    const int TPB = 256;
    const int gN  = (NN + TPB - 1) / TPB;      // 196
    const int gAgg = NN / 4;                   // 12500

    // prep (cvt | wp1 | wp2 | zero+detect)
    k_prep<<<3125 + 128 + 128 + 196, 256, 0, stream>>>(x, W1, W2, xb, wp1, wp2, cursor, e32, flag);

    // CSR build
    k_count<<<GE, TPB, 0, stream>>>(e32, e64, flag, cursor);
    k_part<<<gN, TPB, 0, stream>>>(cursor, bsum);
    k_scanb<<<1, 256, 0, stream>>>(bsum, boff, row_ptr, gN);
    k_addb<<<gN, TPB, 0, stream>>>(cursor, boff, row_ptr, cursor);
    k_fill<<<GE, TPB, 0, stream>>>(e32, e64, flag, cursor, col);

    // layer 1
    k_gemm_mfma<F1, HC1, H1, 256><<<GM1, 256, 0, stream>>>(xb, wp1, as1w, ad1w, h1b, as1, ad1, NN);
    k_agg1<<<gAgg, TPB, 0, stream>>>(row_ptr, col, h1b, as1, ad1, b1, h2in);

    // layer 2
    k_gemm_mfma<HC1, HC2, 1, 128><<<GM1, 128, 0, stream>>>(h2in, wp2, as2w, ad2w, h2b, as2, ad2, NN);
    k_agg2<<<gAgg, TPB, 0, stream>>>(row_ptr, col, h2b, as2, ad2, b2, out);
}

// Round 14
// 237.135 us; speedup vs baseline: 1.9437x; 1.0008x over previous
//
#include <hip/hip_runtime.h>

#define NN 50000
#define NE 800000

constexpr int H1 = 4, F1 = 128, HC1 = 256;
constexpr int HC2 = 128;
constexpr int GM1 = (NN + 63) / 64;     // 782 gemm blocks
constexpr int GE  = (NE + 255) / 256;   // 3125 edge blocks

typedef unsigned short u16;
typedef unsigned int u32;
typedef __attribute__((ext_vector_type(8))) short bf16x8;
typedef __attribute__((ext_vector_type(4))) float f32x4;

__device__ __forceinline__ float bf2f(u16 h) {
    return __uint_as_float(((u32)h) << 16);
}
__device__ __forceinline__ u16 f2bf(float f) {
    u32 u = __float_as_uint(f);
    u32 r = (u + 0x7fffu + ((u >> 16) & 1u)) >> 16;   // RTN-even
    return (u16)r;
}

__device__ __forceinline__ int ld_edge(const int* e32, const long long* e64, int is64, long long idx) {
    return is64 ? (int)e64[idx] : e32[idx];
}

// ---------------- fused prep:
// [0,3125) x->bf16 | [3125,3253) wp1 | [3253,3381) wp2 | 3381 detect | [3382,6507) degree count
__global__ __launch_bounds__(256) void k_prep(
    const float* __restrict__ x, const float* __restrict__ W1, const float* __restrict__ W2,
    u16* __restrict__ xb, u16* __restrict__ wp1, u16* __restrict__ wp2,
    int* __restrict__ deg, const int* __restrict__ e32, const long long* __restrict__ e64,
    int* __restrict__ flag)
{
    const int b = blockIdx.x, tid = threadIdx.x;
    if (b < 3125) {                       // cvt: 3125*256*8 == NN*F1
        int i = b * 256 + tid;
        const float4* p = (const float4*)x + (size_t)i * 2;
        float4 a = p[0], c = p[1];
        ushort4 o0, o1;
        o0.x = f2bf(a.x); o0.y = f2bf(a.y); o0.z = f2bf(a.z); o0.w = f2bf(a.w);
        o1.x = f2bf(c.x); o1.y = f2bf(c.y); o1.z = f2bf(c.z); o1.w = f2bf(c.w);
        ((ushort4*)xb)[(size_t)i * 2] = o0;
        ((ushort4*)xb)[(size_t)i * 2 + 1] = o1;
    } else if (b < 3253) {                // wp1: [NK][256][4][8] <- W1[128][256]
        int o = (b - 3125) * 256 + tid;
        int j = o & 7, lk = (o >> 3) & 3, nn = (o >> 5) & 255, kc = o >> 13;
        int k = kc * 32 + lk * 8 + j;
        wp1[o] = f2bf(W1[(size_t)k * HC1 + nn]);
    } else if (b < 3381) {                // wp2: [NK][128][4][8] <- W2[256][128]
        int o = (b - 3253) * 256 + tid;
        int j = o & 7, lk = (o >> 3) & 3, nn = (o >> 5) & 127, kc = o >> 12;
        int k = kc * 32 + lk * 8 + j;
        wp2[o] = f2bf(W2[(size_t)k * HC2 + nn]);
    } else if (b == 3381) {               // int64 detect (for k_fill)
        if (tid == 0) {
            int z = 1;
            for (int t = 0; t < 16; t++)
                if (e32[2 * t + 1] != 0) z = 0;
            *flag = z;
        }
    } else {                              // degree count (self-detecting is64)
        int e = (b - 3382) * 256 + tid;
        if (e < NE) {
            int z = 1;
            #pragma unroll
            for (int t = 0; t < 16; t++) z &= (e32[2 * t + 1] == 0);  // uniform -> scalar loads
            int dst = z ? (int)e64[(long long)NE + e] : e32[(long long)NE + e];
            atomicAdd(&deg[dst], 1);
        }
    }
}

__global__ __launch_bounds__(256) void k_part(const int* __restrict__ deg, int* __restrict__ bsum) {
    int i = blockIdx.x * 256 + threadIdx.x;
    int v = (i < NN) ? deg[i] : 0;
    #pragma unroll
    for (int off = 1; off < 64; off <<= 1) v += __shfl_xor(v, off);
    __shared__ int ws[4];
    if ((threadIdx.x & 63) == 0) ws[threadIdx.x >> 6] = v;
    __syncthreads();
    if (threadIdx.x == 0) bsum[blockIdx.x] = ws[0] + ws[1] + ws[2] + ws[3];
}

__global__ __launch_bounds__(256) void k_scanb(const int* __restrict__ bsum, int* __restrict__ boff,
                                               int* __restrict__ row_ptr, int NB) {
    const int tid = threadIdx.x;
    const int lane = tid & 63, wv = tid >> 6;
    int v = (tid < NB) ? bsum[tid] : 0;
    int x = v;
    #pragma unroll
    for (int off = 1; off < 64; off <<= 1) {
        int t = __shfl_up(x, off);
        if (lane >= off) x += t;
    }
    __shared__ int wsum[4], woff[4];
    if (lane == 63) wsum[wv] = x;
    __syncthreads();
    if (tid == 0) {
        int run = 0;
        #pragma unroll
        for (int j = 0; j < 4; j++) { woff[j] = run; run += wsum[j]; }
        row_ptr[NN] = run;
    }
    __syncthreads();
    if (tid < NB) boff[tid] = x - v + woff[wv];
}

__global__ __launch_bounds__(256) void k_addb(const int* __restrict__ deg, const int* __restrict__ boff,
                                              int* __restrict__ row_ptr, int* __restrict__ cursor) {
    const int tid = threadIdx.x;
    const int lane = tid & 63, wv = tid >> 6;
    int i = blockIdx.x * 256 + tid;
    int v = (i < NN) ? deg[i] : 0;
    int x = v;
    #pragma unroll
    for (int off = 1; off < 64; off <<= 1) {
        int t = __shfl_up(x, off);
        if (lane >= off) x += t;
    }
    __shared__ int wsum[4], woff[4];
    if (lane == 63) wsum[wv] = x;
    __syncthreads();
    if (tid == 0) {
        int run = 0;
        #pragma unroll
        for (int j = 0; j < 4; j++) { woff[j] = run; run += wsum[j]; }
    }
    __syncthreads();
    int excl = x - v + woff[wv] + boff[blockIdx.x];
    if (i < NN) { row_ptr[i] = excl; cursor[i] = excl; }
}

__global__ void k_fill(const int* __restrict__ e32, const long long* __restrict__ e64,
                       const int* __restrict__ flag, int* __restrict__ cursor, int* __restrict__ col) {
    int e = blockIdx.x * blockDim.x + threadIdx.x;
    if (e >= NE) return;
    int is64 = *flag;
    int src = ld_edge(e32, e64, is64, e);
    int dst = ld_edge(e32, e64, is64, (long long)NE + e);
    int pos = atomicAdd(&cursor[dst], 1);
    col[pos] = src;
}

// ---------------- MFMA GEMM body (+ attention-logit epilogue) ----------------
template <int K, int NOUT, int HEADS, int TPB>
__device__ __forceinline__ void gemm_body(
    int bid, const u16* __restrict__ Ab, const u16* __restrict__ Wp,
    const float* __restrict__ atts, const float* __restrict__ attd,
    u16* __restrict__ Hout, float* __restrict__ as_out, float* __restrict__ ad_out, int M)
{
    constexpr int BM = 64, BK = 32;
    constexpr int NK = K / BK;
    constexpr int C = NOUT / HEADS;
    constexpr int LDA = 40;                         // u16 per LDS row (80 B padded)
    __shared__ __align__(16) u16 As[2][BM * LDA];
    __shared__ float red_s[BM * HEADS];
    __shared__ float red_d[BM * HEADS];

    const int tid = threadIdx.x;
    const int w = tid >> 6;
    const int l = tid & 63;
    const int l15 = l & 15, lk = l >> 4;
    const int row0 = bid * BM;
    const int col0 = w * 64;

    for (int i = tid; i < BM * HEADS; i += TPB) { red_s[i] = 0.f; red_d[i] = 0.f; }

    f32x4 acc[4][4];
    #pragma unroll
    for (int rt = 0; rt < 4; rt++)
        #pragma unroll
        for (int nt = 0; nt < 4; nt++)
            acc[rt][nt] = (f32x4){0.f, 0.f, 0.f, 0.f};

    auto stage = [&](int kc, int b) {
        #pragma unroll
        for (int i = tid; i < BM * 4; i += TPB) {
            int r = i >> 2, c = (i & 3) * 8;
            int gr = row0 + r;
            bf16x8 v = {0, 0, 0, 0, 0, 0, 0, 0};
            if (gr < M) v = *(const bf16x8*)(Ab + (size_t)gr * K + kc * BK + c);
            *(bf16x8*)&As[b][r * LDA + c] = v;
        }
    };
    auto loadB = [&](int kc, bf16x8* bf) {
        #pragma unroll
        for (int nt = 0; nt < 4; nt++)
            bf[nt] = *(const bf16x8*)(Wp + (((size_t)kc * NOUT + col0 + nt * 16 + l15) * 4 + lk) * 8);
    };

    bf16x8 bcur[4];
    loadB(0, bcur);
    stage(0, 0);
    for (int kc = 0; kc < NK; ++kc) {
        __syncthreads();
        bf16x8 afr[4];
        #pragma unroll
        for (int rt = 0; rt < 4; rt++)
            afr[rt] = *(const bf16x8*)&As[kc & 1][(rt * 16 + l15) * LDA + lk * 8];
        bf16x8 bnext[4];
        if (kc + 1 < NK) {
            loadB(kc + 1, bnext);
            stage(kc + 1, (kc + 1) & 1);
        }
        #pragma unroll
        for (int rt = 0; rt < 4; rt++)
            #pragma unroll
            for (int nt = 0; nt < 4; nt++)
                acc[rt][nt] = __builtin_amdgcn_mfma_f32_16x16x32_bf16(afr[rt], bcur[nt], acc[rt][nt], 0, 0, 0);
        if (kc + 1 < NK) {
            #pragma unroll
            for (int nt = 0; nt < 4; nt++) bcur[nt] = bnext[nt];
        }
    }

    // D layout col=l&15, row=(l>>4)*4+t  [m89-verified]
    #pragma unroll
    for (int rt = 0; rt < 4; rt++) {
        #pragma unroll
        for (int t = 0; t < 4; t++) {
            int gr = row0 + rt * 16 + lk * 4 + t;
            if (gr < M) {
                #pragma unroll
                for (int nt = 0; nt < 4; nt++)
                    Hout[(size_t)gr * NOUT + col0 + nt * 16 + l15] = f2bf(acc[rt][nt][t]);
            }
        }
    }

    float avs[4], avd[4];
    #pragma unroll
    for (int nt = 0; nt < 4; nt++) {
        int gc = col0 + nt * 16 + l15;
        avs[nt] = atts[gc];
        avd[nt] = attd[gc];
    }
    const int headw = col0 / C;
    #pragma unroll
    for (int rt = 0; rt < 4; rt++) {
        #pragma unroll
        for (int t = 0; t < 4; t++) {
            float ps = 0.f, pd = 0.f;
            #pragma unroll
            for (int nt = 0; nt < 4; nt++) {
                ps = fmaf(acc[rt][nt][t], avs[nt], ps);
                pd = fmaf(acc[rt][nt][t], avd[nt], pd);
            }
            ps += __shfl_xor(ps, 1); ps += __shfl_xor(ps, 2);
            ps += __shfl_xor(ps, 4); ps += __shfl_xor(ps, 8);
            pd += __shfl_xor(pd, 1); pd += __shfl_xor(pd, 2);
            pd += __shfl_xor(pd, 4); pd += __shfl_xor(pd, 8);
            if (l15 == 0) {
                int row = rt * 16 + lk * 4 + t;
                atomicAdd(&red_s[row * HEADS + headw], ps);
                atomicAdd(&red_d[row * HEADS + headw], pd);
            }
        }
    }
    __syncthreads();
    for (int i = tid; i < BM * HEADS; i += TPB) {
        int gr = row0 + i / HEADS;
        if (gr < M) {
            as_out[(size_t)gr * HEADS + i % HEADS] = red_s[i];
            ad_out[(size_t)gr * HEADS + i % HEADS] = red_d[i];
        }
    }
}

template <int K, int NOUT, int HEADS, int TPB>
__global__ __launch_bounds__(TPB) void k_gemm_mfma(
    const u16* __restrict__ Ab, const u16* __restrict__ Wp,
    const float* __restrict__ atts, const float* __restrict__ attd,
    u16* __restrict__ Hout, float* __restrict__ as_out, float* __restrict__ ad_out, int M)
{
    gemm_body<K, NOUT, HEADS, TPB>(blockIdx.x, Ab, Wp, atts, attd, Hout, as_out, ad_out, M);
}

// ---------------- aggregation layer 1: R6 measured-best form (1 edge/iter, 32 VGPR) -----------
__global__ __launch_bounds__(256) void k_agg1(
    const int* __restrict__ row_ptr, const int* __restrict__ col,
    const u16* __restrict__ Hb, const float* __restrict__ as_, const float* __restrict__ ad_,
    const float* __restrict__ bias, u16* __restrict__ outp)
{
    __shared__ int    s_src[4][64];
    __shared__ float4 s_p[4][64];
    int n = blockIdx.x * 4 + (threadIdx.x >> 6);
    if (n >= NN) return;
    const int lane = threadIdx.x & 63;
    const int wv = threadIdx.x >> 6;
    const int head = lane >> 4;                 // channels lane*4..lane*4+3 live in head lane>>4
    float4 ad4 = *(const float4*)(ad_ + (size_t)n * 4);
    int beg = row_ptr[n];
    int cnt = row_ptr[n + 1] - beg + 1;         // +1: self loop first
    float4 sp = make_float4(0.f, 0.f, 0.f, 0.f);
    float ax = 0.f, ay = 0.f, az = 0.f, aw = 0.f;
    for (int c = 0; c < cnt; c += 64) {
        int idx = c + lane;
        int srcl = n;
        float4 p4 = make_float4(0.f, 0.f, 0.f, 0.f);
        if (idx < cnt) {
            srcl = (idx == 0) ? n : col[beg + idx - 1];
            float4 a4 = *(const float4*)(as_ + (size_t)srcl * 4);
            float e;
            e = a4.x + ad4.x; e = e > 0.f ? e : 0.2f * e; p4.x = __expf(e);
            e = a4.y + ad4.y; e = e > 0.f ? e : 0.2f * e; p4.y = __expf(e);
            e = a4.z + ad4.z; e = e > 0.f ? e : 0.2f * e; p4.z = __expf(e);
            e = a4.w + ad4.w; e = e > 0.f ? e : 0.2f * e; p4.w = __expf(e);
        }
        sp.x += p4.x; sp.y += p4.y; sp.z += p4.z; sp.w += p4.w;
        s_src[wv][lane] = srcl;
        s_p[wv][lane] = p4;
        int jmax = min(64, cnt - c);
        #pragma unroll 4
        for (int j = 0; j < jmax; ++j) {
            int srcj = s_src[wv][j];                          // uniform -> broadcast
            float pj = ((const float*)&s_p[wv][j])[head];     // 4 banks, 16-lane broadcast each
            ushort4 hv = *(const ushort4*)(Hb + (size_t)srcj * HC1 + lane * 4);
            ax = fmaf(pj, bf2f(hv.x), ax);
            ay = fmaf(pj, bf2f(hv.y), ay);
            az = fmaf(pj, bf2f(hv.z), az);
            aw = fmaf(pj, bf2f(hv.w), aw);
        }
    }
    #pragma unroll
    for (int off = 1; off < 64; off <<= 1) {
        sp.x += __shfl_xor(sp.x, off);
        sp.y += __shfl_xor(sp.y, off);
        sp.z += __shfl_xor(sp.z, off);
        sp.w += __shfl_xor(sp.w, off);
    }
    float s = head < 2 ? (head == 0 ? sp.x : sp.y) : (head == 2 ? sp.z : sp.w);
    float inv = 1.f / s;
    float4 bv = *(const float4*)(bias + lane * 4);
    float4 o;
    o.x = ax * inv + bv.x;
    o.y = ay * inv + bv.y;
    o.z = az * inv + bv.z;
    o.w = aw * inv + bv.w;
    o.x = o.x > 0.f ? o.x : __expf(o.x) - 1.f;   // ELU
    o.y = o.y > 0.f ? o.y : __expf(o.y) - 1.f;
    o.z = o.z > 0.f ? o.z : __expf(o.z) - 1.f;
    o.w = o.w > 0.f ? o.w : __expf(o.w) - 1.f;
    ushort4 ob;
    ob.x = f2bf(o.x); ob.y = f2bf(o.y); ob.z = f2bf(o.z); ob.w = f2bf(o.w);
    *(ushort4*)(outp + (size_t)n * HC1 + lane * 4) = ob;
}

// ---------------- aggregation layer 2: 2 edges/iter (2x32 lanes), 8B/lane ushort4 gather --------
__global__ __launch_bounds__(256) void k_agg2(
    const int* __restrict__ row_ptr, const int* __restrict__ col,
    const u16* __restrict__ Hb, const float* __restrict__ as_, const float* __restrict__ ad_,
    const float* __restrict__ bias, float* __restrict__ outp)
{
    __shared__ int   s_src[4][64];
    __shared__ float s_p[4][64];
    int n = blockIdx.x * 4 + (threadIdx.x >> 6);
    const int lane = threadIdx.x & 63;
    const int wv = threadIdx.x >> 6;
    const int half = lane >> 5, l32 = lane & 31;
    float ad0 = ad_[n];
    int beg = row_ptr[n];
    int cnt = row_ptr[n + 1] - beg + 1;
    float sp = 0.f;
    float a0 = 0.f, a1 = 0.f, a2 = 0.f, a3 = 0.f;
    for (int c = 0; c < cnt; c += 64) {
        int idx = c + lane;
        int srcl = n;
        float p = 0.f;
        if (idx < cnt) {
            srcl = (idx == 0) ? n : col[beg + idx - 1];
            float e = as_[srcl] + ad0;
            e = e > 0.f ? e : 0.2f * e;
            p = __expf(e);
        }
        sp += p;
        s_src[wv][lane] = srcl;
        s_p[wv][lane] = p;
        int jmax = min(64, cnt - c);
        #pragma unroll 4
        for (int j = 0; j < jmax; j += 2) {
            int jj = j + half;
            int srcj = s_src[wv][jj];
            float pj = s_p[wv][jj];
            ushort4 hv = *(const ushort4*)(Hb + (size_t)srcj * HC2 + l32 * 4);
            a0 = fmaf(pj, bf2f(hv.x), a0);
            a1 = fmaf(pj, bf2f(hv.y), a1);
            a2 = fmaf(pj, bf2f(hv.z), a2);
            a3 = fmaf(pj, bf2f(hv.w), a3);
        }
    }
    a0 += __shfl_xor(a0, 32); a1 += __shfl_xor(a1, 32);
    a2 += __shfl_xor(a2, 32); a3 += __shfl_xor(a3, 32);
    #pragma unroll
    for (int off = 1; off < 64; off <<= 1) sp += __shfl_xor(sp, off);
    if (lane < 32) {
        float inv = 1.f / sp;
        int ch0 = l32 * 4;
        float4 bv = *(const float4*)(bias + ch0);
        float4 o;
        o.x = a0 * inv + bv.x;
        o.y = a1 * inv + bv.y;
        o.z = a2 * inv + bv.z;
        o.w = a3 * inv + bv.w;
        *(float4*)(outp + (size_t)n * HC2 + ch0) = o;
    }
}

// ---------------- launch ----------------
extern "C" void kernel_launch(void* const* d_in, const int* in_sizes, int n_in,
                              void* d_out, int out_size, void* d_ws, size_t ws_size,
                              hipStream_t stream) {
    const float* x   = (const float*)d_in[0];
    const int*       e32 = (const int*)d_in[1];
    const long long* e64 = (const long long*)d_in[1];
    const float* W1  = (const float*)d_in[2];
    const float* as1w = (const float*)d_in[3];
    const float* ad1w = (const float*)d_in[4];
    const float* b1  = (const float*)d_in[5];
    const float* W2  = (const float*)d_in[6];
    const float* as2w = (const float*)d_in[7];
    const float* ad2w = (const float*)d_in[8];
    const float* b2  = (const float*)d_in[9];
    float* out = (float*)d_out;

    char* w = (char*)d_ws;
    auto carve = [&](size_t bytes) -> void* {
        void* p = (void*)w;
        w += (bytes + 255) & ~(size_t)255;
        return p;
    };
    int*   flag    = (int*)carve(4);
    int*   row_ptr = (int*)carve((NN + 1) * sizeof(int));
    int*   cursor  = (int*)carve(NN * sizeof(int));
    int*   col     = (int*)carve(NE * sizeof(int));
    int*   bsum    = (int*)carve(256 * sizeof(int));
    int*   boff    = (int*)carve(256 * sizeof(int));
    float* as1     = (float*)carve((size_t)NN * H1 * sizeof(float));
    float* ad1     = (float*)carve((size_t)NN * H1 * sizeof(float));
    float* as2     = (float*)carve((size_t)NN * sizeof(float));
    float* ad2     = (float*)carve((size_t)NN * sizeof(float));
    u16*   xb      = (u16*)carve((size_t)NN * F1 * sizeof(u16));
    u16*   h1b     = (u16*)carve((size_t)NN * HC1 * sizeof(u16));
    u16*   h2in    = (u16*)carve((size_t)NN * HC1 * sizeof(u16));
    u16*   h2b     = (u16*)carve((size_t)NN * HC2 * sizeof(u16));
    u16*   wp1     = (u16*)carve((size_t)F1 * HC1 * sizeof(u16));
    u16*   wp2     = (u16*)carve((size_t)HC1 * HC2 * sizeof(u16));

    const int TPB = 256;
    const int gN  = (NN + TPB - 1) / TPB;      // 196
    const int gAgg = NN / 4;                   // 12500

    // zero degrees (stream-ordered, graph-safe)
    hipMemsetAsync(cursor, 0, NN * sizeof(int), stream);

    // prep (cvt | wp1 | wp2 | detect | degree count) — copies overlap atomics
    k_prep<<<3382 + GE, 256, 0, stream>>>(x, W1, W2, xb, wp1, wp2, cursor, e32, e64, flag);

    // CSR scan + fill
    k_part<<<gN, TPB, 0, stream>>>(cursor, bsum);
    k_scanb<<<1, 256, 0, stream>>>(bsum, boff, row_ptr, gN);
    k_addb<<<gN, TPB, 0, stream>>>(cursor, boff, row_ptr, cursor);
    k_fill<<<GE, TPB, 0, stream>>>(e32, e64, flag, cursor, col);

    // layer 1
    k_gemm_mfma<F1, HC1, H1, 256><<<GM1, 256, 0, stream>>>(xb, wp1, as1w, ad1w, h1b, as1, ad1, NN);
    k_agg1<<<gAgg, TPB, 0, stream>>>(row_ptr, col, h1b, as1, ad1, b1, h2in);

    // layer 2
    k_gemm_mfma<HC1, HC2, 1, 128><<<GM1, 128, 0, stream>>>(h2in, wp2, as2w, ad2w, h2b, as2, ad2, NN);
    k_agg2<<<gAgg, TPB, 0, stream>>>(row_ptr, col, h2b, as2, ad2, b2, out);
}

// Round 15
// 229.507 us; speedup vs baseline: 2.0083x; 1.0332x over previous
//
#include <hip/hip_runtime.h>

#define NN 50000
#define NE 800000

constexpr int H1 = 4, F1 = 128, HC1 = 256;
constexpr int HC2 = 128;
constexpr int GM1 = (NN + 63) / 64;     // 782 gemm blocks
constexpr int GE  = (NE + 255) / 256;   // 3125 edge blocks
constexpr int GN  = (NN + 255) / 256;   // 196 node blocks

typedef unsigned short u16;
typedef unsigned int u32;
typedef __attribute__((ext_vector_type(8))) short bf16x8;
typedef __attribute__((ext_vector_type(4))) float f32x4;

__device__ __forceinline__ float bf2f(u16 h) {
    return __uint_as_float(((u32)h) << 16);
}
__device__ __forceinline__ u16 f2bf(float f) {
    u32 u = __float_as_uint(f);
    u32 r = (u + 0x7fffu + ((u >> 16) & 1u)) >> 16;   // RTN-even
    return (u16)r;
}

__device__ __forceinline__ int ld_edge(const int* e32, const long long* e64, int is64, long long idx) {
    return is64 ? (int)e64[idx] : e32[idx];
}

// ---------------- fused prep:
// [0,128) wp1 | [128,256) wp2 | 256 detect | [257,257+GE) degree count
__global__ __launch_bounds__(256) void k_prep(
    const float* __restrict__ W1, const float* __restrict__ W2,
    u16* __restrict__ wp1, u16* __restrict__ wp2,
    int* __restrict__ deg, const int* __restrict__ e32, const long long* __restrict__ e64,
    int* __restrict__ flag)
{
    const int b = blockIdx.x, tid = threadIdx.x;
    if (b < 128) {                        // wp1: [NK][256][4][8] <- W1[128][256]
        int o = b * 256 + tid;
        int j = o & 7, lk = (o >> 3) & 3, nn = (o >> 5) & 255, kc = o >> 13;
        int k = kc * 32 + lk * 8 + j;
        wp1[o] = f2bf(W1[(size_t)k * HC1 + nn]);
    } else if (b < 256) {                 // wp2: [NK][128][4][8] <- W2[256][128]
        int o = (b - 128) * 256 + tid;
        int j = o & 7, lk = (o >> 3) & 3, nn = (o >> 5) & 127, kc = o >> 12;
        int k = kc * 32 + lk * 8 + j;
        wp2[o] = f2bf(W2[(size_t)k * HC2 + nn]);
    } else if (b == 256) {                // int64 detect (for k_fill)
        if (tid == 0) {
            int z = 1;
            for (int t = 0; t < 16; t++)
                if (e32[2 * t + 1] != 0) z = 0;
            *flag = z;
        }
    } else {                              // degree count (self-detecting is64)
        int e = (b - 257) * 256 + tid;
        if (e < NE) {
            int z = 1;
            #pragma unroll
            for (int t = 0; t < 16; t++) z &= (e32[2 * t + 1] == 0);  // uniform -> scalar loads
            int dst = z ? (int)e64[(long long)NE + e] : e32[(long long)NE + e];
            atomicAdd(&deg[dst], 1);
        }
    }
}

__global__ __launch_bounds__(256) void k_part(const int* __restrict__ deg, int* __restrict__ bsum) {
    int i = blockIdx.x * 256 + threadIdx.x;
    int v = (i < NN) ? deg[i] : 0;
    #pragma unroll
    for (int off = 1; off < 64; off <<= 1) v += __shfl_xor(v, off);
    __shared__ int ws[4];
    if ((threadIdx.x & 63) == 0) ws[threadIdx.x >> 6] = v;
    __syncthreads();
    if (threadIdx.x == 0) bsum[blockIdx.x] = ws[0] + ws[1] + ws[2] + ws[3];
}

// block prefix via in-block masked reduction of bsum (redundant per block, fully parallel)
__global__ __launch_bounds__(256) void k_addb(const int* __restrict__ deg, const int* __restrict__ bsum,
                                              int* __restrict__ row_ptr, int* __restrict__ cursor) {
    const int tid = threadIdx.x;
    const int lane = tid & 63, wv = tid >> 6;
    const int b = blockIdx.x;
    __shared__ int wsum[4], woff[4], s_pref[4], s_tot[4];

    // masked reductions over the GN block sums
    int bs = (tid < GN) ? bsum[tid] : 0;
    int vp = (tid < b) ? bs : 0;          // prefix for this block
    int vt = bs;                          // total
    #pragma unroll
    for (int off = 1; off < 64; off <<= 1) {
        vp += __shfl_xor(vp, off);
        vt += __shfl_xor(vt, off);
    }
    if (lane == 0) { s_pref[wv] = vp; s_tot[wv] = vt; }
    __syncthreads();
    int pref = s_pref[0] + s_pref[1] + s_pref[2] + s_pref[3];
    if (b == 0 && tid == 0)
        row_ptr[NN] = s_tot[0] + s_tot[1] + s_tot[2] + s_tot[3];

    // local exclusive scan of this block's 256 degrees
    int i = b * 256 + tid;
    int v = (i < NN) ? deg[i] : 0;
    int x = v;
    #pragma unroll
    for (int off = 1; off < 64; off <<= 1) {
        int t = __shfl_up(x, off);
        if (lane >= off) x += t;
    }
    if (lane == 63) wsum[wv] = x;
    __syncthreads();
    if (tid == 0) {
        int run = 0;
        #pragma unroll
        for (int j = 0; j < 4; j++) { woff[j] = run; run += wsum[j]; }
    }
    __syncthreads();
    int excl = x - v + woff[wv] + pref;
    if (i < NN) { row_ptr[i] = excl; cursor[i] = excl; }
}

__global__ void k_fill(const int* __restrict__ e32, const long long* __restrict__ e64,
                       const int* __restrict__ flag, int* __restrict__ cursor, int* __restrict__ col) {
    int e = blockIdx.x * blockDim.x + threadIdx.x;
    if (e >= NE) return;
    int is64 = *flag;
    int src = ld_edge(e32, e64, is64, e);
    int dst = ld_edge(e32, e64, is64, (long long)NE + e);
    int pos = atomicAdd(&cursor[dst], 1);
    col[pos] = src;
}

// ---------------- MFMA GEMM body (+ attention-logit epilogue) ----------------
// AF32=1: A is f32, converted to bf16 during staging (TPB must be 256).
template <int K, int NOUT, int HEADS, int TPB, int AF32>
__device__ __forceinline__ void gemm_body(
    int bid, const void* __restrict__ Ain, const u16* __restrict__ Wp,
    const float* __restrict__ atts, const float* __restrict__ attd,
    u16* __restrict__ Hout, float* __restrict__ as_out, float* __restrict__ ad_out, int M)
{
    constexpr int BM = 64, BK = 32;
    constexpr int NK = K / BK;
    constexpr int C = NOUT / HEADS;
    constexpr int LDA = 40;                         // u16 per LDS row (80 B padded)
    __shared__ __align__(16) u16 As[2][BM * LDA];
    __shared__ float red_s[BM * HEADS];
    __shared__ float red_d[BM * HEADS];

    const int tid = threadIdx.x;
    const int w = tid >> 6;
    const int l = tid & 63;
    const int l15 = l & 15, lk = l >> 4;
    const int row0 = bid * BM;
    const int col0 = w * 64;

    for (int i = tid; i < BM * HEADS; i += TPB) { red_s[i] = 0.f; red_d[i] = 0.f; }

    f32x4 acc[4][4];
    #pragma unroll
    for (int rt = 0; rt < 4; rt++)
        #pragma unroll
        for (int nt = 0; nt < 4; nt++)
            acc[rt][nt] = (f32x4){0.f, 0.f, 0.f, 0.f};

    auto stage = [&](int kc, int b) {
        if constexpr (AF32) {
            const float* Af = (const float*)Ain;   // 4 thr/row, 8 f32 each
            int r = tid >> 2, c = (tid & 3) * 8;
            int gr = row0 + r;
            float4 f0 = make_float4(0.f, 0.f, 0.f, 0.f), f1 = f0;
            if (gr < M) {
                f0 = *(const float4*)(Af + (size_t)gr * K + kc * BK + c);
                f1 = *(const float4*)(Af + (size_t)gr * K + kc * BK + c + 4);
            }
            bf16x8 v;
            v[0] = (short)f2bf(f0.x); v[1] = (short)f2bf(f0.y);
            v[2] = (short)f2bf(f0.z); v[3] = (short)f2bf(f0.w);
            v[4] = (short)f2bf(f1.x); v[5] = (short)f2bf(f1.y);
            v[6] = (short)f2bf(f1.z); v[7] = (short)f2bf(f1.w);
            *(bf16x8*)&As[b][r * LDA + c] = v;
        } else {
            const u16* Ab = (const u16*)Ain;
            #pragma unroll
            for (int i = tid; i < BM * 4; i += TPB) {
                int r = i >> 2, c = (i & 3) * 8;
                int gr = row0 + r;
                bf16x8 v = {0, 0, 0, 0, 0, 0, 0, 0};
                if (gr < M) v = *(const bf16x8*)(Ab + (size_t)gr * K + kc * BK + c);
                *(bf16x8*)&As[b][r * LDA + c] = v;
            }
        }
    };
    auto loadB = [&](int kc, bf16x8* bf) {
        #pragma unroll
        for (int nt = 0; nt < 4; nt++)
            bf[nt] = *(const bf16x8*)(Wp + (((size_t)kc * NOUT + col0 + nt * 16 + l15) * 4 + lk) * 8);
    };

    bf16x8 bcur[4];
    loadB(0, bcur);
    stage(0, 0);
    for (int kc = 0; kc < NK; ++kc) {
        __syncthreads();
        bf16x8 afr[4];
        #pragma unroll
        for (int rt = 0; rt < 4; rt++)
            afr[rt] = *(const bf16x8*)&As[kc & 1][(rt * 16 + l15) * LDA + lk * 8];
        bf16x8 bnext[4];
        if (kc + 1 < NK) {
            loadB(kc + 1, bnext);
            stage(kc + 1, (kc + 1) & 1);
        }
        #pragma unroll
        for (int rt = 0; rt < 4; rt++)
            #pragma unroll
            for (int nt = 0; nt < 4; nt++)
                acc[rt][nt] = __builtin_amdgcn_mfma_f32_16x16x32_bf16(afr[rt], bcur[nt], acc[rt][nt], 0, 0, 0);
        if (kc + 1 < NK) {
            #pragma unroll
            for (int nt = 0; nt < 4; nt++) bcur[nt] = bnext[nt];
        }
    }

    // D layout col=l&15, row=(l>>4)*4+t  [m89-verified]
    #pragma unroll
    for (int rt = 0; rt < 4; rt++) {
        #pragma unroll
        for (int t = 0; t < 4; t++) {
            int gr = row0 + rt * 16 + lk * 4 + t;
            if (gr < M) {
                #pragma unroll
                for (int nt = 0; nt < 4; nt++)
                    Hout[(size_t)gr * NOUT + col0 + nt * 16 + l15] = f2bf(acc[rt][nt][t]);
            }
        }
    }

    float avs[4], avd[4];
    #pragma unroll
    for (int nt = 0; nt < 4; nt++) {
        int gc = col0 + nt * 16 + l15;
        avs[nt] = atts[gc];
        avd[nt] = attd[gc];
    }
    const int headw = col0 / C;
    #pragma unroll
    for (int rt = 0; rt < 4; rt++) {
        #pragma unroll
        for (int t = 0; t < 4; t++) {
            float ps = 0.f, pd = 0.f;
            #pragma unroll
            for (int nt = 0; nt < 4; nt++) {
                ps = fmaf(acc[rt][nt][t], avs[nt], ps);
                pd = fmaf(acc[rt][nt][t], avd[nt], pd);
            }
            ps += __shfl_xor(ps, 1); ps += __shfl_xor(ps, 2);
            ps += __shfl_xor(ps, 4); ps += __shfl_xor(ps, 8);
            pd += __shfl_xor(pd, 1); pd += __shfl_xor(pd, 2);
            pd += __shfl_xor(pd, 4); pd += __shfl_xor(pd, 8);
            if (l15 == 0) {
                int row = rt * 16 + lk * 4 + t;
                atomicAdd(&red_s[row * HEADS + headw], ps);
                atomicAdd(&red_d[row * HEADS + headw], pd);
            }
        }
    }
    __syncthreads();
    for (int i = tid; i < BM * HEADS; i += TPB) {
        int gr = row0 + i / HEADS;
        if (gr < M) {
            as_out[(size_t)gr * HEADS + i % HEADS] = red_s[i];
            ad_out[(size_t)gr * HEADS + i % HEADS] = red_d[i];
        }
    }
}

template <int K, int NOUT, int HEADS, int TPB, int AF32>
__global__ __launch_bounds__(TPB) void k_gemm_mfma(
    const void* __restrict__ Ain, const u16* __restrict__ Wp,
    const float* __restrict__ atts, const float* __restrict__ attd,
    u16* __restrict__ Hout, float* __restrict__ as_out, float* __restrict__ ad_out, int M)
{
    gemm_body<K, NOUT, HEADS, TPB, AF32>(blockIdx.x, Ain, Wp, atts, attd, Hout, as_out, ad_out, M);
}

// ---------------- aggregation layer 1: measured-best form (1 edge/iter, 32 VGPR) -----------
__global__ __launch_bounds__(256) void k_agg1(
    const int* __restrict__ row_ptr, const int* __restrict__ col,
    const u16* __restrict__ Hb, const float* __restrict__ as_, const float* __restrict__ ad_,
    const float* __restrict__ bias, u16* __restrict__ outp)
{
    __shared__ int    s_src[4][64];
    __shared__ float4 s_p[4][64];
    int n = blockIdx.x * 4 + (threadIdx.x >> 6);
    if (n >= NN) return;
    const int lane = threadIdx.x & 63;
    const int wv = threadIdx.x >> 6;
    const int head = lane >> 4;                 // channels lane*4..lane*4+3 live in head lane>>4
    float4 ad4 = *(const float4*)(ad_ + (size_t)n * 4);
    int beg = row_ptr[n];
    int cnt = row_ptr[n + 1] - beg + 1;         // +1: self loop first
    float4 sp = make_float4(0.f, 0.f, 0.f, 0.f);
    float ax = 0.f, ay = 0.f, az = 0.f, aw = 0.f;
    for (int c = 0; c < cnt; c += 64) {
        int idx = c + lane;
        int srcl = n;
        float4 p4 = make_float4(0.f, 0.f, 0.f, 0.f);
        if (idx < cnt) {
            srcl = (idx == 0) ? n : col[beg + idx - 1];
            float4 a4 = *(const float4*)(as_ + (size_t)srcl * 4);
            float e;
            e = a4.x + ad4.x; e = e > 0.f ? e : 0.2f * e; p4.x = __expf(e);
            e = a4.y + ad4.y; e = e > 0.f ? e : 0.2f * e; p4.y = __expf(e);
            e = a4.z + ad4.z; e = e > 0.f ? e : 0.2f * e; p4.z = __expf(e);
            e = a4.w + ad4.w; e = e > 0.f ? e : 0.2f * e; p4.w = __expf(e);
        }
        sp.x += p4.x; sp.y += p4.y; sp.z += p4.z; sp.w += p4.w;
        s_src[wv][lane] = srcl;
        s_p[wv][lane] = p4;
        int jmax = min(64, cnt - c);
        #pragma unroll 4
        for (int j = 0; j < jmax; ++j) {
            int srcj = s_src[wv][j];                          // uniform -> broadcast
            float pj = ((const float*)&s_p[wv][j])[head];     // 4 banks, 16-lane broadcast each
            ushort4 hv = *(const ushort4*)(Hb + (size_t)srcj * HC1 + lane * 4);
            ax = fmaf(pj, bf2f(hv.x), ax);
            ay = fmaf(pj, bf2f(hv.y), ay);
            az = fmaf(pj, bf2f(hv.z), az);
            aw = fmaf(pj, bf2f(hv.w), aw);
        }
    }
    #pragma unroll
    for (int off = 1; off < 64; off <<= 1) {
        sp.x += __shfl_xor(sp.x, off);
        sp.y += __shfl_xor(sp.y, off);
        sp.z += __shfl_xor(sp.z, off);
        sp.w += __shfl_xor(sp.w, off);
    }
    float s = head < 2 ? (head == 0 ? sp.x : sp.y) : (head == 2 ? sp.z : sp.w);
    float inv = 1.f / s;
    float4 bv = *(const float4*)(bias + lane * 4);
    float4 o;
    o.x = ax * inv + bv.x;
    o.y = ay * inv + bv.y;
    o.z = az * inv + bv.z;
    o.w = aw * inv + bv.w;
    o.x = o.x > 0.f ? o.x : __expf(o.x) - 1.f;   // ELU
    o.y = o.y > 0.f ? o.y : __expf(o.y) - 1.f;
    o.z = o.z > 0.f ? o.z : __expf(o.z) - 1.f;
    o.w = o.w > 0.f ? o.w : __expf(o.w) - 1.f;
    ushort4 ob;
    ob.x = f2bf(o.x); ob.y = f2bf(o.y); ob.z = f2bf(o.z); ob.w = f2bf(o.w);
    *(ushort4*)(outp + (size_t)n * HC1 + lane * 4) = ob;
}

// ---------------- aggregation layer 2: 2 edges/iter (2x32 lanes), 8B/lane ushort4 gather --------
__global__ __launch_bounds__(256) void k_agg2(
    const int* __restrict__ row_ptr, const int* __restrict__ col,
    const u16* __restrict__ Hb, const float* __restrict__ as_, const float* __restrict__ ad_,
    const float* __restrict__ bias, float* __restrict__ outp)
{
    __shared__ int   s_src[4][64];
    __shared__ float s_p[4][64];
    int n = blockIdx.x * 4 + (threadIdx.x >> 6);
    const int lane = threadIdx.x & 63;
    const int wv = threadIdx.x >> 6;
    const int half = lane >> 5, l32 = lane & 31;
    float ad0 = ad_[n];
    int beg = row_ptr[n];
    int cnt = row_ptr[n + 1] - beg + 1;
    float sp = 0.f;
    float a0 = 0.f, a1 = 0.f, a2 = 0.f, a3 = 0.f;
    for (int c = 0; c < cnt; c += 64) {
        int idx = c + lane;
        int srcl = n;
        float p = 0.f;
        if (idx < cnt) {
            srcl = (idx == 0) ? n : col[beg + idx - 1];
            float e = as_[srcl] + ad0;
            e = e > 0.f ? e : 0.2f * e;
            p = __expf(e);
        }
        sp += p;
        s_src[wv][lane] = srcl;
        s_p[wv][lane] = p;
        int jmax = min(64, cnt - c);
        #pragma unroll 4
        for (int j = 0; j < jmax; j += 2) {
            int jj = j + half;
            int srcj = s_src[wv][jj];
            float pj = s_p[wv][jj];
            ushort4 hv = *(const ushort4*)(Hb + (size_t)srcj * HC2 + l32 * 4);
            a0 = fmaf(pj, bf2f(hv.x), a0);
            a1 = fmaf(pj, bf2f(hv.y), a1);
            a2 = fmaf(pj, bf2f(hv.z), a2);
            a3 = fmaf(pj, bf2f(hv.w), a3);
        }
    }
    a0 += __shfl_xor(a0, 32); a1 += __shfl_xor(a1, 32);
    a2 += __shfl_xor(a2, 32); a3 += __shfl_xor(a3, 32);
    #pragma unroll
    for (int off = 1; off < 64; off <<= 1) sp += __shfl_xor(sp, off);
    if (lane < 32) {
        float inv = 1.f / sp;
        int ch0 = l32 * 4;
        float4 bv = *(const float4*)(bias + ch0);
        float4 o;
        o.x = a0 * inv + bv.x;
        o.y = a1 * inv + bv.y;
        o.z = a2 * inv + bv.z;
        o.w = a3 * inv + bv.w;
        *(float4*)(outp + (size_t)n * HC2 + ch0) = o;
    }
}

// ---------------- launch ----------------
extern "C" void kernel_launch(void* const* d_in, const int* in_sizes, int n_in,
                              void* d_out, int out_size, void* d_ws, size_t ws_size,
                              hipStream_t stream) {
    const float* x   = (const float*)d_in[0];
    const int*       e32 = (const int*)d_in[1];
    const long long* e64 = (const long long*)d_in[1];
    const float* W1  = (const float*)d_in[2];
    const float* as1w = (const float*)d_in[3];
    const float* ad1w = (const float*)d_in[4];
    const float* b1  = (const float*)d_in[5];
    const float* W2  = (const float*)d_in[6];
    const float* as2w = (const float*)d_in[7];
    const float* ad2w = (const float*)d_in[8];
    const float* b2  = (const float*)d_in[9];
    float* out = (float*)d_out;

    char* w = (char*)d_ws;
    auto carve = [&](size_t bytes) -> void* {
        void* p = (void*)w;
        w += (bytes + 255) & ~(size_t)255;
        return p;
    };
    int*   flag    = (int*)carve(4);
    int*   row_ptr = (int*)carve((NN + 1) * sizeof(int));
    int*   cursor  = (int*)carve(NN * sizeof(int));
    int*   col     = (int*)carve(NE * sizeof(int));
    int*   bsum    = (int*)carve(256 * sizeof(int));
    float* as1     = (float*)carve((size_t)NN * H1 * sizeof(float));
    float* ad1     = (float*)carve((size_t)NN * H1 * sizeof(float));
    float* as2     = (float*)carve((size_t)NN * sizeof(float));
    float* ad2     = (float*)carve((size_t)NN * sizeof(float));
    u16*   h1b     = (u16*)carve((size_t)NN * HC1 * sizeof(u16));
    u16*   h2in    = (u16*)carve((size_t)NN * HC1 * sizeof(u16));
    u16*   h2b     = (u16*)carve((size_t)NN * HC2 * sizeof(u16));
    u16*   wp1     = (u16*)carve((size_t)F1 * HC1 * sizeof(u16));
    u16*   wp2     = (u16*)carve((size_t)HC1 * HC2 * sizeof(u16));

    const int TPB = 256;
    const int gAgg = NN / 4;                   // 12500

    // zero degrees (stream-ordered, graph-safe)
    hipMemsetAsync(cursor, 0, NN * sizeof(int), stream);

    // prep (wp1 | wp2 | detect | degree count)
    k_prep<<<257 + GE, 256, 0, stream>>>(W1, W2, wp1, wp2, cursor, e32, e64, flag);

    // CSR scan + fill
    k_part<<<GN, TPB, 0, stream>>>(cursor, bsum);
    k_addb<<<GN, TPB, 0, stream>>>(cursor, bsum, row_ptr, cursor);
    k_fill<<<GE, TPB, 0, stream>>>(e32, e64, flag, cursor, col);

    // layer 1 (gemm reads x f32 directly; stage converts)
    k_gemm_mfma<F1, HC1, H1, 256, 1><<<GM1, 256, 0, stream>>>(
        (const void*)x, wp1, as1w, ad1w, h1b, as1, ad1, NN);
    k_agg1<<<gAgg, TPB, 0, stream>>>(row_ptr, col, h1b, as1, ad1, b1, h2in);

    // layer 2
    k_gemm_mfma<HC1, HC2, 1, 128, 0><<<GM1, 128, 0, stream>>>(
        (const void*)h2in, wp2, as2w, ad2w, h2b, as2, ad2, NN);
    k_agg2<<<gAgg, TPB, 0, stream>>>(row_ptr, col, h2b, as2, ad2, b2, out);
}